// Round 7
// baseline (193.582 us; speedup 1.0000x reference)
//
#include <hip/hip_runtime.h>
#include <hip/hip_bf16.h>

// B=4, S=2048, D=512. fp32 in/out, bf16 MFMA internals.
// Key identity: multiplicative causal mask => E = 1 + F, F = expm1(scale*s) on
// the lower triangle (q>=k), 0 above. Then
//   out  = F @ vp'  +  T,   T[b,d] = sum_k vp'[b,k,d]
//   Z[k] = 2048 + colsum(F)
// Pipeline: cvt_all | proj3 | scoresF | scaleT | outF
//
// R6: proj/scores core -> B-IN-REGISTERS: B (weights / kp) is L2-resident by
//     construction, so its fragments are read straight from global as per-lane
//     16B loads (64 lanes = 16 rows x 64B contiguous = perfect line use).
//     LDS halves to an A-only double buffer (32 KB) => 3 blocks/CU
//     (launch_bounds(256,3)), staging VMEM ops halve. Manual vmcnt ledger
//     (SCHEDB-pinned order): [8 B-loads][4 glds16 A(i+1)] WAITV(12) = A(i)
//     landed, B(i)+A(i+1) in flight; tail WAITV(8). outF/cvt/scale keep the
//     R4b-proven form; outF mapping reverted to R4b linear.

#define S_LEN 2048
#define D_DIM 512
#define SCALE_F 0.044194173824159216f  // 1/sqrt(512)

typedef __attribute__((ext_vector_type(8))) short s8v;   // 8 bf16 = 4 VGPRs
typedef __attribute__((ext_vector_type(4))) short s4v;   // 4 bf16 = 8 B
typedef __attribute__((ext_vector_type(4))) float f4v;   // MFMA accumulator

enum { EPI_BIAS = 0, EPI_BIAS_T = 1, EPI_SCORES = 2 };

#define SBAR()    __builtin_amdgcn_s_barrier()
#define SCHEDB()  __builtin_amdgcn_sched_barrier(0)
#define WAITV(n)  asm volatile("s_waitcnt vmcnt(" #n ")")
#define WAITL0()  asm volatile("s_waitcnt lgkmcnt(0)")

__device__ __forceinline__ short f2bf_s(float f) {
  union { __hip_bfloat16 b; short s; } u; u.b = __float2bfloat16(f); return u.s;
}
__device__ __forceinline__ float bf2f_s(short h) {
  union { short s; __hip_bfloat16 b; } u; u.s = h; return __bfloat162float(u.b);
}

__device__ __forceinline__ void glds16(const short* g, short* l) {
  __builtin_amdgcn_global_load_lds((const __attribute__((address_space(1))) void*)g,
                                   (__attribute__((address_space(3))) void*)l, 16, 0, 0);
}

// LDS byte offset of a __shared__-derived pointer (addrspace(3) is 32-bit).
__device__ __forceinline__ unsigned lds_addr(const short* p) {
  return (unsigned)(unsigned long long)(const __attribute__((address_space(3))) short*)p;
}

// Inline-asm ds_read_b128: keeps the counted WAITV authoritative. MUST be
// followed by lgkmcnt(0)+SCHEDB before any consumer (rule 18).
__device__ __forceinline__ s8v dsr128(unsigned a) {
  s8v r;
  asm volatile("ds_read_b128 %0, %1" : "=&v"(r) : "v"(a));
  return r;
}

// Core NT GEMM, 128x128 tile at (m0,n0), K=512 (8 K-tiles of 64).
// A: LDS double buffer (2 x 16 KB), staged via glds16, asm ds_read fragments.
// B: registers, straight from global/L2 (row-major NT: B[n][k]).
// Per iter kt: B(kt)->regs (8 loads) | glds16 A(kt+1) (4) | WAITV(12) |
// SBAR | 2 phases {4 asm ds_read A, lgkmcnt(0), setprio(1), 16 MFMA}.
template <int EPI>
__device__ __forceinline__ void gemm_core512(
    const short* __restrict__ A, const short* __restrict__ B,
    short* __restrict__ C, const float* __restrict__ bias,
    short* SMEM, int N, size_t sCz, int m0, int n0, int bz,
    float* __restrict__ Z)
{
  const int tid  = threadIdx.x;
  const int w    = tid >> 6;
  const int lane = tid & 63;
  const int quad = lane >> 4;
  const int l16  = lane & 15;
  const int wm   = (w >> 1) * 64;
  const int wn   = (w & 1) * 64;

  const int strow = tid >> 3;                         // 0..31
  const int gl = ((tid & 7) ^ (strow & 7)) * 8;       // XOR column-octet swizzle

  f4v acc[4][4];
#pragma unroll
  for (int i = 0; i < 4; ++i)
#pragma unroll
    for (int j = 0; j < 4; ++j)
#pragma unroll
      for (int r = 0; r < 4; ++r) acc[i][j][r] = 0.0f;

  const short* Ag = A + (size_t)(m0 + strow) * 512 + gl;
  const size_t pstr = (size_t)32 * 512;
  const int t8 = tid * 8;
  const int swq = l16 & 7;

  // B fragment base: row n0+wn+l16 (+j*16 rows per rep), k-window quad*8.
  const short* Bf = B + (size_t)(n0 + wn + l16) * 512 + (quad << 3);

  const unsigned base = lds_addr(SMEM);
  unsigned aoff[4];
#pragma unroll
  for (int ii = 0; ii < 4; ++ii)
    aoff[ii] = base + (unsigned)((wm + ii * 16 + l16) * 128 + ((quad ^ swq) * 16));

  // stage A tile kt into LDS buffer b (4 glds16/thread)
#define STAGEA(kt, b)                                                          \
  {                                                                            \
    short* dst_ = SMEM + (b) * 8192 + t8;                                      \
    const int ko_ = (kt) << 6;                                                 \
    _Pragma("unroll")                                                          \
    for (int p = 0; p < 4; ++p) glds16(Ag + ko_ + p * pstr, dst_ + p * 2048);  \
  }

  STAGEA(0, 0);

  for (int kt = 0; kt < 8; ++kt) {
    const int c = kt & 1;

    // B(kt) fragments -> registers (compiler emits its own waits for these)
    s8v bcur[2][4];
#pragma unroll
    for (int kk = 0; kk < 2; ++kk)
#pragma unroll
      for (int j = 0; j < 4; ++j)
        bcur[kk][j] = *(const s8v*)(Bf + j * (16 * 512) + (kt << 6) + (kk << 5));
    SCHEDB();

    if (kt < 7) {
      STAGEA(kt + 1, 1 - c);
      SCHEDB();
      WAITV(12);   // outstanding: A(kt)4 oldest, B(kt)8, A(kt+1)4 -> A(kt) done
    } else {
      WAITV(8);    // outstanding: A(7)4, B(7)8 -> A(7) done
    }
    SBAR();
    SCHEDB();

    const unsigned cofs = (unsigned)(c << 14);   // c * 16384 bytes
#pragma unroll
    for (int kk = 0; kk < 2; ++kk) {
      const unsigned kx = (unsigned)(kk << 6);
      s8v af[4];
#pragma unroll
      for (int ii = 0; ii < 4; ++ii) af[ii] = dsr128((aoff[ii] ^ kx) + cofs);
      WAITL0();
      SCHEDB();
      __builtin_amdgcn_s_setprio(1);
#pragma unroll
      for (int ii = 0; ii < 4; ++ii)
#pragma unroll
        for (int j = 0; j < 4; ++j)
          acc[ii][j] = __builtin_amdgcn_mfma_f32_16x16x32_bf16(af[ii], bcur[kk][j], acc[ii][j], 0, 0, 0);
      __builtin_amdgcn_s_setprio(0);
    }
  }
#undef STAGEA

  // ---- epilogue ----
  float bv[4];
  if (EPI == EPI_BIAS || EPI == EPI_BIAS_T) {
#pragma unroll
    for (int j = 0; j < 4; ++j) bv[j] = bias[n0 + wn + j * 16 + l16];
  }

  if (EPI == EPI_BIAS_T) {
#pragma unroll
    for (int i = 0; i < 4; ++i) {
#pragma unroll
      for (int j = 0; j < 4; ++j) {
        const int gn  = n0 + wn + j * 16 + l16;
        const int gmb = m0 + wm + i * 16 + quad * 4;
        const int bb = gmb >> 11, ssb = gmb & (S_LEN - 1);
        s4v o;
#pragma unroll
        for (int r = 0; r < 4; ++r) o[r] = f2bf_s(acc[i][j][r] + bv[j]);
        *(s4v*)&C[((size_t)bb * D_DIM + gn) * S_LEN + ssb] = o;
      }
    }
    return;
  }

  // EPI_BIAS / EPI_SCORES: LDS transpose -> coalesced 16B row stores.
  short* TB = SMEM;                 // 4 waves x 2176 shorts (32 rows x stride 68)
  const int wbase = w * 2176;
  float csum[4] = {0.f, 0.f, 0.f, 0.f};

#pragma unroll
  for (int ph = 0; ph < 2; ++ph) {
    __syncthreads();
#pragma unroll
    for (int ii = 0; ii < 2; ++ii) {
      const int i = ph * 2 + ii;
#pragma unroll
      for (int j = 0; j < 4; ++j) {
        const int gn = n0 + wn + j * 16 + l16;
#pragma unroll
        for (int r = 0; r < 4; ++r) {
          short o;
          if (EPI == EPI_SCORES) {
            const int gm = m0 + wm + i * 16 + quad * 4 + r;
            const float f = (gm >= gn) ? (__expf(acc[i][j][r] * SCALE_F) - 1.0f) : 0.0f;
            csum[j] += f;
            o = f2bf_s(f);
          } else {
            o = f2bf_s(acc[i][j][r] + bv[j]);
          }
          TB[wbase + (ii * 16 + quad * 4 + r) * 68 + j * 16 + l16] = o;
        }
      }
    }
    __syncthreads();
#pragma unroll
    for (int p = 0; p < 4; ++p) {
      const int row = p * 8 + (lane >> 3);   // 0..31
      const int cg  = lane & 7;
      const s8v vv = *(const s8v*)&TB[wbase + row * 68 + cg * 8];
      const int gm = m0 + wm + ph * 32 + row;
      const int gn = n0 + wn + cg * 8;
      *(s8v*)&C[sCz + (size_t)gm * N + gn] = vv;
    }
  }

  if (EPI == EPI_SCORES) {
#pragma unroll
    for (int j = 0; j < 4; ++j) {
      float cs = csum[j];
      cs += __shfl_xor(cs, 16, 64);
      cs += __shfl_xor(cs, 32, 64);
      if (quad == 0) atomicAdd(&Z[(bz << 11) + n0 + wn + j * 16 + l16], cs);
    }
  }
}

// scores-F kernel: 1-D grid 544 (=8x68, XCD-bijective swizzle), tri tiles.
// One batch per 2 XCDs => that batch's kp (2 MB) is L2-resident for B-reads.
__global__ __launch_bounds__(256, 3) void gemm_scoresF(
    const short* __restrict__ A, const short* __restrict__ B, short* __restrict__ C,
    float* __restrict__ Z)
{
  __shared__ __align__(16) short SMEM[16384];   // 32 KB (A dbuf only)
  const int bid = blockIdx.x;
  const int bsw = (bid & 7) * 68 + (bid >> 3);  // consecutive bsw share one XCD
  const int bz  = bsw / 136;
  const int t   = bsw - bz * 136;
  int ti = (int)((sqrtf(8.0f * t + 1.0f) - 1.0f) * 0.5f);
  while ((ti + 1) * (ti + 2) / 2 <= t) ++ti;
  while (ti * (ti + 1) / 2 > t) --ti;
  const int tj = t - ti * (ti + 1) / 2;         // tj <= ti
  gemm_core512<EPI_SCORES>(A + (size_t)bz * S_LEN * D_DIM, B + (size_t)bz * S_LEN * D_DIM,
                           C, nullptr, SMEM, S_LEN,
                           (size_t)bz * S_LEN * S_LEN, ti * 128, tj * 128, bz, Z);
}

// projections: 1-D grid 768 (=8x96, XCD-bijective swizzle), z from id.
// B = weights (512 KB) -> L2-resident for B-reads.
__global__ __launch_bounds__(256, 3) void proj3(
    const short* __restrict__ a0, const short* __restrict__ a1, const short* __restrict__ a2,
    const short* __restrict__ b0, const short* __restrict__ b1, const short* __restrict__ b2,
    short* __restrict__ c0, short* __restrict__ c1, short* __restrict__ c2,
    const float* __restrict__ x0, const float* __restrict__ x1, const float* __restrict__ x2)
{
  __shared__ __align__(16) short SMEM[16384];   // 32 KB (A dbuf only)
  const int bid = blockIdx.x;
  const int bsw = (bid & 7) * 96 + (bid >> 3);
  const int z   = bsw >> 8;
  const int rem = bsw & 255;
  const int m0  = (rem >> 2) * 128;
  const int n0  = (rem & 3) * 128;
  const short* A = (z == 0) ? a0 : (z == 1) ? a1 : a2;
  const short* B = (z == 0) ? b0 : (z == 1) ? b1 : b2;
  short*       C = (z == 0) ? c0 : (z == 1) ? c1 : c2;
  const float* bias = (z == 0) ? x0 : (z == 1) ? x1 : x2;
  if (z == 2)
    gemm_core512<EPI_BIAS_T>(A, B, C, bias, SMEM, D_DIM, 0, m0, n0, 0, nullptr);
  else
    gemm_core512<EPI_BIAS>(A, B, C, bias, SMEM, D_DIM, 0, m0, n0, 0, nullptr);
}

// out = F @ vpT'^T + T, 64x128 tiles, BK=64, K truncated at m0+64,
// triple-buffered (72 KB), prefetch distance 2 issued AFTER the barrier.
// Grid 512 1-D (R4b mapping): h -> n0=(h&3)*128, bz=(h>>2)&3, zs=h>>4;
// co-resident pairs (h, h+256) get complementary niter (sum 33).
__global__ __launch_bounds__(256, 2) void gemm_outF(
    const short* __restrict__ F, const short* __restrict__ vpT,
    const float* __restrict__ Tv, float* __restrict__ out)
{
  __shared__ __align__(16) short SMEM[36864];   // 72 KB

  const int tid  = threadIdx.x;
  const int h    = blockIdx.x;
  const int n0   = (h & 3) * 128;
  const int bz   = (h >> 2) & 3;
  const int zs   = h >> 4;                      // 0..31
  const int mi   = (zs < 16) ? (31 - zs) : (zs - 16);
  const int m0   = mi * 64;

  const short* A = F   + (size_t)bz * S_LEN * S_LEN;
  const short* B = vpT + (size_t)bz * D_DIM * S_LEN;

  const int w    = tid >> 6;
  const int lane = tid & 63;
  const int quad = lane >> 4;
  const int l16  = lane & 15;
  const int wm   = (w >> 1) * 32;
  const int wn   = (w & 1) * 64;

  const int strow = tid >> 3;
  const int gl = ((tid & 7) ^ (strow & 7)) * 8;

  f4v acc[2][4];
#pragma unroll
  for (int i = 0; i < 2; ++i)
#pragma unroll
    for (int j = 0; j < 4; ++j)
#pragma unroll
      for (int r = 0; r < 4; ++r) acc[i][j][r] = 0.0f;

  const short* Ag = A + (size_t)(m0 + strow) * S_LEN + gl;
  const short* Bg = B + (size_t)(n0 + strow) * S_LEN + gl;
  const size_t pstr = (size_t)32 * S_LEN;
  const int t8 = tid * 8;
  const int swq = l16 & 7;

  const unsigned base = lds_addr(SMEM);
  unsigned aoff[2], boff[4];
#pragma unroll
  for (int ii = 0; ii < 2; ++ii)
    aoff[ii] = base + (unsigned)((wm + ii * 16 + l16) * 128 + ((quad ^ swq) * 16));
#pragma unroll
  for (int j = 0; j < 4; ++j)
    boff[j] = base + 8192u + (unsigned)((wn + j * 16 + l16) * 128 + ((quad ^ swq) * 16));

  const int niter = mi + 1;   // K runs 0 .. m0+64

  // preload tiles 0,1 into bufs 0,1 (6 loads each: A x2, B x4)
#pragma unroll
  for (int pre = 0; pre < 2; ++pre) {
    short* dst = SMEM + pre * 12288 + t8;
    const int k0 = pre << 6;
#pragma unroll
    for (int p = 0; p < 2; ++p) glds16(Ag + k0 + p * pstr, dst + p * 2048);
#pragma unroll
    for (int p = 0; p < 4; ++p) glds16(Bg + k0 + p * pstr, dst + 4096 + p * 2048);
  }

  int cbuf = 0;
  for (int i = 0; i < niter; ++i) {
    if (i + 1 < niter) { WAITV(6); } else { WAITV(0); }   // tile i landed
    SBAR();
    SCHEDB();

    if (i + 2 < niter) {          // issue i+2 into the buffer read at i-1
      int nb = cbuf + 2; if (nb >= 3) nb -= 3;
      const int k2 = (i + 2) << 6;
      short* dst = SMEM + nb * 12288 + t8;
#pragma unroll
      for (int p = 0; p < 2; ++p) glds16(Ag + k2 + p * pstr, dst + p * 2048);
#pragma unroll
      for (int p = 0; p < 4; ++p) glds16(Bg + k2 + p * pstr, dst + 4096 + p * 2048);
      SCHEDB();
    }

    const unsigned cofs = (unsigned)(cbuf * 24576);
    cbuf = (cbuf == 2) ? 0 : cbuf + 1;
#pragma unroll
    for (int kk = 0; kk < 2; ++kk) {
      const unsigned kx = (unsigned)(kk << 6);
      s8v af[2], bf[4];
#pragma unroll
      for (int ii = 0; ii < 2; ++ii) af[ii] = dsr128((aoff[ii] ^ kx) + cofs);
#pragma unroll
      for (int j = 0; j < 4; ++j)   bf[j]  = dsr128((boff[j] ^ kx) + cofs);
      WAITL0();
      SCHEDB();
      __builtin_amdgcn_s_setprio(1);
#pragma unroll
      for (int ii = 0; ii < 2; ++ii)
#pragma unroll
        for (int j = 0; j < 4; ++j)
          acc[ii][j] = __builtin_amdgcn_mfma_f32_16x16x32_bf16(af[ii], bf[j], acc[ii][j], 0, 0, 0);
      __builtin_amdgcn_s_setprio(0);
    }
  }

  float* Cf = out + (size_t)bz * S_LEN * D_DIM;
#pragma unroll
  for (int i = 0; i < 2; ++i) {
#pragma unroll
    for (int j = 0; j < 4; ++j) {
      const int gn = n0 + wn + j * 16 + l16;
      const float tvn = Tv[(bz << 9) + gn];
#pragma unroll
      for (int r = 0; r < 4; ++r) {
        const int gm = m0 + wm + i * 16 + quad * 4 + r;
        Cf[(size_t)gm * D_DIM + gn] = acc[i][j][r] + tvn;
      }
    }
  }
}

// fp32 -> bf16, one launch for data (x<2048) and weights (x>=2048).
__global__ __launch_bounds__(256) void cvt_all(
    const float* __restrict__ q, const float* __restrict__ k, const float* __restrict__ v,
    const float* __restrict__ wq, const float* __restrict__ wk, const float* __restrict__ wv,
    short* __restrict__ qb, short* __restrict__ Wqb)
{
  const int y = blockIdx.y;
  const float* s; short* d; int i;
  if (blockIdx.x < 2048) {
    s = (y == 0) ? q : (y == 1) ? k : v;
    d = qb + (size_t)y * 4194304;
    i = (blockIdx.x * 256 + threadIdx.x) * 8;
  } else {
    s = (y == 0) ? wq : (y == 1) ? wk : wv;
    d = Wqb + (size_t)y * 262144;
    i = ((int)(blockIdx.x - 2048) * 256 + threadIdx.x) * 8;
  }
  const float4 f0 = *(const float4*)(s + i);
  const float4 f1 = *(const float4*)(s + i + 4);
  s8v o;
  o[0] = f2bf_s(f0.x); o[1] = f2bf_s(f0.y); o[2] = f2bf_s(f0.z); o[3] = f2bf_s(f0.w);
  o[4] = f2bf_s(f1.x); o[5] = f2bf_s(f1.y); o[6] = f2bf_s(f1.z); o[7] = f2bf_s(f1.w);
  *(s8v*)(d + i) = o;
}

// block per (b,d): vpT[b][d][k] /= (2048+ZF[b][k]); Tv[b,d] = sum_k (fp32)
__global__ __launch_bounds__(256) void scale_vpt_T(
    short* __restrict__ vpT, const float* __restrict__ ZF, float* __restrict__ Tv)
{
  __shared__ float red[4];
  const int b = blockIdx.y, d = blockIdx.x, tid = threadIdx.x;
  const size_t rowbase = ((size_t)(b * D_DIM + d)) * S_LEN;
  const float* zf = ZF + (b << 11);
  const int k0 = tid * 8;

  s8v v = *(s8v*)&vpT[rowbase + k0];
  float s = 0.0f;
#pragma unroll
  for (int i = 0; i < 8; ++i) {
    const float w = bf2f_s(v[i]) / (2048.0f + zf[k0 + i]);
    s += w;
    v[i] = f2bf_s(w);
  }
  *(s8v*)&vpT[rowbase + k0] = v;

#pragma unroll
  for (int off = 32; off >= 1; off >>= 1) s += __shfl_xor(s, off, 64);
  if ((tid & 63) == 0) red[tid >> 6] = s;
  __syncthreads();
  if (tid == 0) Tv[(b << 9) + d] = red[0] + red[1] + red[2] + red[3];
}

extern "C" void kernel_launch(void* const* d_in, const int* in_sizes, int n_in,
                              void* d_out, int out_size, void* d_ws, size_t ws_size,
                              hipStream_t stream) {
  const float* q   = (const float*)d_in[0];
  const float* k   = (const float*)d_in[1];
  const float* v   = (const float*)d_in[2];
  const float* WQw = (const float*)d_in[3];
  const float* WQb = (const float*)d_in[4];
  const float* WKw = (const float*)d_in[5];
  const float* WKb = (const float*)d_in[6];
  const float* WVw = (const float*)d_in[7];
  const float* WVb = (const float*)d_in[8];

  char* ws = (char*)d_ws;
  // F occupies [0,32M); bf16 input/weight copies alias its head (dead before F written)
  short* F   = (short*)(ws);                 // 32 MB  [4][2048][2048] (lower tiles only)
  short* qb  = (short*)(ws);                 //  8 MB  (qb,kb,vb contiguous)
  short* Wqb = (short*)(ws + 25165824);      // 3x 512 KB contiguous
  short* qp  = (short*)(ws + 33554432);      //  8 MB  [4][2048][512]
  short* kp  = (short*)(ws + 41943040);      //  8 MB
  short* vpT = (short*)(ws + 50331648);      //  8 MB  [4][512][2048]
  float* ZF  = (float*)(ws + 58720256);      // 32 KB  [4][2048]
  float* Tv  = (float*)(ws + 58753024);      //  8 KB  [4][512]
  short* kb  = qb + 4194304;
  short* vb  = qb + 8388608;
  short* Wkb = Wqb + 262144;
  short* Wvb = Wqb + 524288;

  const dim3 blk(256);

  (void)hipMemsetAsync(ZF, 0, 4 * S_LEN * sizeof(float), stream);

  cvt_all<<<dim3(2176, 3), blk, 0, stream>>>(q, k, v, WQw, WKw, WVw, qb, Wqb);

  // projections: M=8192, N=512, K=512 — 768 blocks, 3/CU, B from L2
  proj3<<<dim3(768), blk, 0, stream>>>(
      qb, kb, vb, Wqb, Wkb, Wvb, qp, kp, vpT, WQb, WKb, WVb);

  // F = expm1(scale*qp@kp^T) lower-tri tiles + fused ZF colsum: 544 blocks
  gemm_scoresF<<<dim3(544), blk, 0, stream>>>(qp, kp, F, ZF);

  // vpT' = vpT/(2048+ZF); Tv = rowsum(vpT')
  scale_vpt_T<<<dim3(512, 4), blk, 0, stream>>>(vpT, ZF, Tv);

  // out = F @ vpT'^T + Tv: 64x128 tiles, K truncated at m0+64, balanced pairs
  gemm_outF<<<dim3(512), blk, 0, stream>>>(F, vpT, Tv, (float*)d_out);
}

// Round 8
// 181.399 us; speedup vs baseline: 1.0672x; 1.0672x over previous
//
#include <hip/hip_runtime.h>
#include <hip/hip_bf16.h>

// B=4, S=2048, D=512. fp32 in/out, bf16 MFMA internals.
// Key identity: multiplicative causal mask => E = 1 + F, F = expm1(scale*s) on
// the lower triangle (q>=k), 0 above. Then
//   out  = F @ vp'  +  T,   T[b,d] = sum_k vp'[b,k,d]
//   Z[k] = 2048 + colsum(F)
// Pipeline: cvt_w(+ZF0) | proj3 (fused fp32 cvt) | scoresF | scaleT | outF
//
// R7: revert R6's B-in-registers (regressed 25us: divergent per-lane B loads
//     serialize against MFMA). Base = R4b (best, 168.5us). New: proj stages A
//     directly from fp32 q/k/v (reg-load float4 -> v_cvt -> ds_write into the
//     same swizzled layout, T14 issue-early/write-late), killing the big cvt
//     kernel + qb slab traffic (48MB read + 24MB write + 24MB re-read -> 48MB
//     L2-local read). B (weights) keeps glds16 with counted ledger:
//     [STB(i+1)] compute(i) WAITV(4)=A-regs WRA LDA(i+2) WAITV(8)=B landed,
//     lgkmcnt(0), ONE barrier/K-tile. ZF memset folded into weights-cvt.
//     scoresF / outF / scale unchanged from R4b.

#define S_LEN 2048
#define D_DIM 512
#define SCALE_F 0.044194173824159216f  // 1/sqrt(512)

typedef __attribute__((ext_vector_type(8))) short s8v;   // 8 bf16 = 4 VGPRs
typedef __attribute__((ext_vector_type(4))) short s4v;   // 4 bf16 = 8 B
typedef __attribute__((ext_vector_type(4))) float f4v;   // MFMA accumulator

enum { EPI_BIAS = 0, EPI_BIAS_T = 1, EPI_SCORES = 2 };

#define SBAR()    __builtin_amdgcn_s_barrier()
#define SCHEDB()  __builtin_amdgcn_sched_barrier(0)
#define WAITV(n)  asm volatile("s_waitcnt vmcnt(" #n ")")
#define WAITL0()  asm volatile("s_waitcnt lgkmcnt(0)")

__device__ __forceinline__ short f2bf_s(float f) {
  union { __hip_bfloat16 b; short s; } u; u.b = __float2bfloat16(f); return u.s;
}
__device__ __forceinline__ float bf2f_s(short h) {
  union { short s; __hip_bfloat16 b; } u; u.s = h; return __bfloat162float(u.b);
}

__device__ __forceinline__ void glds16(const short* g, short* l) {
  __builtin_amdgcn_global_load_lds((const __attribute__((address_space(1))) void*)g,
                                   (__attribute__((address_space(3))) void*)l, 16, 0, 0);
}

// LDS byte offset of a __shared__-derived pointer (addrspace(3) is 32-bit).
__device__ __forceinline__ unsigned lds_addr(const short* p) {
  return (unsigned)(unsigned long long)(const __attribute__((address_space(3))) short*)p;
}

// Inline-asm ds_read_b128: keeps the counted WAITV authoritative. MUST be
// followed by lgkmcnt(0)+SCHEDB before any consumer (rule 18).
__device__ __forceinline__ s8v dsr128(unsigned a) {
  s8v r;
  asm volatile("ds_read_b128 %0, %1" : "=&v"(r) : "v"(a));
  return r;
}

// ---------------------------------------------------------------------------
// gemm_core (R4b): NT GEMM, 128x128 tile, BK=64, LDS double buffer (64 KB),
// both operands via glds16. Used by scoresF.
template <int EPI>
__device__ __forceinline__ void gemm_core(
    const short* __restrict__ A, const short* __restrict__ B,
    short* __restrict__ C, const float* __restrict__ bias,
    short* SMEM, int N, int K, size_t sCz, int m0, int n0, int bz,
    float* __restrict__ Z)
{
  const int tid  = threadIdx.x;
  const int w    = tid >> 6;
  const int lane = tid & 63;
  const int quad = lane >> 4;
  const int l16  = lane & 15;
  const int wm   = (w >> 1) * 64;
  const int wn   = (w & 1) * 64;

  const int strow = tid >> 3;                         // 0..31
  const int gl = ((tid & 7) ^ (strow & 7)) * 8;       // XOR column-octet swizzle

  f4v acc[4][4];
#pragma unroll
  for (int i = 0; i < 4; ++i)
#pragma unroll
    for (int j = 0; j < 4; ++j)
#pragma unroll
      for (int r = 0; r < 4; ++r) acc[i][j][r] = 0.0f;

  const short* Ag = A + (size_t)(m0 + strow) * K + gl;
  const short* Bg = B + (size_t)(n0 + strow) * K + gl;
  const size_t pstr = (size_t)32 * K;
  const int t8 = tid * 8;
  const int swq = l16 & 7;

  const unsigned base = lds_addr(SMEM);
  unsigned aoff[4], boff[4];
#pragma unroll
  for (int ii = 0; ii < 4; ++ii)
    aoff[ii] = base + (unsigned)((wm + ii * 16 + l16) * 128 + ((quad ^ swq) * 16));
#pragma unroll
  for (int j = 0; j < 4; ++j)
    boff[j] = base + 16384u + (unsigned)((wn + j * 16 + l16) * 128 + ((quad ^ swq) * 16));

  const int niter = K >> 6;

#pragma unroll
  for (int p = 0; p < 4; ++p) glds16(Ag + p * pstr, SMEM + t8 + p * 2048);
#pragma unroll
  for (int p = 0; p < 4; ++p) glds16(Bg + p * pstr, SMEM + 8192 + t8 + p * 2048);

  for (int i = 0; i < niter; ++i) {
    const int c = i & 1;
    if (i + 1 < niter) {
      const int k1 = (i + 1) << 6;
      short* dA = SMEM + (1 - c) * 16384 + t8;
#pragma unroll
      for (int p = 0; p < 4; ++p) glds16(Ag + k1 + p * pstr, dA + p * 2048);
#pragma unroll
      for (int p = 0; p < 4; ++p) glds16(Bg + k1 + p * pstr, dA + 8192 + p * 2048);
      SCHEDB();
      WAITV(8);          // tile i landed; tile i+1's 8 stay in flight
    } else {
      WAITV(0);
    }
    SBAR();
    SCHEDB();

    const unsigned cofs = (unsigned)(c << 15);
#pragma unroll
    for (int kk = 0; kk < 2; ++kk) {
      const unsigned kx = (unsigned)(kk << 6);
      s8v af[4], bf[4];
#pragma unroll
      for (int ii = 0; ii < 4; ++ii) af[ii] = dsr128((aoff[ii] ^ kx) + cofs);
#pragma unroll
      for (int j = 0; j < 4; ++j)   bf[j]  = dsr128((boff[j] ^ kx) + cofs);
      WAITL0();
      SCHEDB();
      __builtin_amdgcn_s_setprio(1);
#pragma unroll
      for (int ii = 0; ii < 4; ++ii)
#pragma unroll
        for (int j = 0; j < 4; ++j)
          acc[ii][j] = __builtin_amdgcn_mfma_f32_16x16x32_bf16(af[ii], bf[j], acc[ii][j], 0, 0, 0);
      __builtin_amdgcn_s_setprio(0);
    }
    SBAR();              // buf c free for next iter's prefetch
  }

  // ---- epilogue ----
  float bv[4];
  if (EPI == EPI_BIAS || EPI == EPI_BIAS_T) {
#pragma unroll
    for (int j = 0; j < 4; ++j) bv[j] = bias[n0 + wn + j * 16 + l16];
  }

  if (EPI == EPI_BIAS_T) {
#pragma unroll
    for (int i = 0; i < 4; ++i) {
#pragma unroll
      for (int j = 0; j < 4; ++j) {
        const int gn  = n0 + wn + j * 16 + l16;
        const int gmb = m0 + wm + i * 16 + quad * 4;
        const int bb = gmb >> 11, ssb = gmb & (S_LEN - 1);
        s4v o;
#pragma unroll
        for (int r = 0; r < 4; ++r) o[r] = f2bf_s(acc[i][j][r] + bv[j]);
        *(s4v*)&C[((size_t)bb * D_DIM + gn) * S_LEN + ssb] = o;
      }
    }
    return;
  }

  // EPI_BIAS / EPI_SCORES: LDS transpose -> coalesced 16B row stores.
  short* TB = SMEM;                 // 4 waves x 2176 shorts (32 rows x stride 68)
  const int wbase = w * 2176;
  float csum[4] = {0.f, 0.f, 0.f, 0.f};

#pragma unroll
  for (int ph = 0; ph < 2; ++ph) {
    __syncthreads();
#pragma unroll
    for (int ii = 0; ii < 2; ++ii) {
      const int i = ph * 2 + ii;
#pragma unroll
      for (int j = 0; j < 4; ++j) {
        const int gn = n0 + wn + j * 16 + l16;
#pragma unroll
        for (int r = 0; r < 4; ++r) {
          short o;
          if (EPI == EPI_SCORES) {
            const int gm = m0 + wm + i * 16 + quad * 4 + r;
            const float f = (gm >= gn) ? (__expf(acc[i][j][r] * SCALE_F) - 1.0f) : 0.0f;
            csum[j] += f;
            o = f2bf_s(f);
          } else {
            o = f2bf_s(acc[i][j][r] + bv[j]);
          }
          TB[wbase + (ii * 16 + quad * 4 + r) * 68 + j * 16 + l16] = o;
        }
      }
    }
    __syncthreads();
#pragma unroll
    for (int p = 0; p < 4; ++p) {
      const int row = p * 8 + (lane >> 3);   // 0..31
      const int cg  = lane & 7;
      const s8v vv = *(const s8v*)&TB[wbase + row * 68 + cg * 8];
      const int gm = m0 + wm + ph * 32 + row;
      const int gn = n0 + wn + cg * 8;
      *(s8v*)&C[sCz + (size_t)gm * N + gn] = vv;
    }
  }

  if (EPI == EPI_SCORES) {
#pragma unroll
    for (int j = 0; j < 4; ++j) {
      float cs = csum[j];
      cs += __shfl_xor(cs, 16, 64);
      cs += __shfl_xor(cs, 32, 64);
      if (quad == 0) atomicAdd(&Z[(bz << 11) + n0 + wn + j * 16 + l16], cs);
    }
  }
}

// ---------------------------------------------------------------------------
// proj_core: as gemm_core but A comes from fp32 global, converted in-flight.
// A: reg-load 2xfloat4 per row-slice -> v_cvt -> ds_write_b128 (same layout).
// B: glds16. Ledger per iter kt: enter with A(kt+1)-regs(8) in flight;
// STB(kt+1)+4 -> compute(kt) -> WAITV(4)=A(kt+1) done -> WRA -> LDA(kt+2)+8
// -> WAITV(8)=B(kt+1) done -> lgkmcnt(0) -> SBAR (one barrier per K-tile).
template <int EPI>
__device__ __forceinline__ void proj_core(
    const float* __restrict__ Af, const short* __restrict__ B,
    short* __restrict__ C, const float* __restrict__ bias,
    short* SMEM, int m0, int n0)
{
  const int tid  = threadIdx.x;
  const int w    = tid >> 6;
  const int lane = tid & 63;
  const int quad = lane >> 4;
  const int l16  = lane & 15;
  const int wm   = (w >> 1) * 64;
  const int wn   = (w & 1) * 64;

  const int strow = tid >> 3;                         // 0..31
  const int gl = ((tid & 7) ^ (strow & 7)) * 8;       // XOR column-octet swizzle

  f4v acc[4][4];
#pragma unroll
  for (int i = 0; i < 4; ++i)
#pragma unroll
    for (int j = 0; j < 4; ++j)
#pragma unroll
      for (int r = 0; r < 4; ++r) acc[i][j][r] = 0.0f;

  const float* AgF = Af + (size_t)(m0 + strow) * 512 + gl;
  const short* Bg  = B + (size_t)(n0 + strow) * 512 + gl;
  const size_t pstr = (size_t)32 * 512;   // elements, 32 rows
  const int t8 = tid * 8;
  const int swq = l16 & 7;

  const unsigned base = lds_addr(SMEM);
  unsigned aoff[4], boff[4];
#pragma unroll
  for (int ii = 0; ii < 4; ++ii)
    aoff[ii] = base + (unsigned)((wm + ii * 16 + l16) * 128 + ((quad ^ swq) * 16));
#pragma unroll
  for (int j = 0; j < 4; ++j)
    boff[j] = base + 16384u + (unsigned)((wn + j * 16 + l16) * 128 + ((quad ^ swq) * 16));

  float4 ar[4][2];   // next A tile, 4 row-slices x 8 floats

#define LDA_P(kt)                                                              \
  { _Pragma("unroll")                                                          \
    for (int p = 0; p < 4; ++p) {                                              \
      const float* s_ = AgF + ((kt) << 6) + p * pstr;                          \
      ar[p][0] = *(const float4*)s_;                                           \
      ar[p][1] = *(const float4*)(s_ + 4);                                     \
    } }
#define STB_P(kt, b)                                                           \
  { short* dst_ = SMEM + (b) * 16384 + 8192 + t8;                              \
    const int ko_ = (kt) << 6;                                                 \
    _Pragma("unroll")                                                          \
    for (int p = 0; p < 4; ++p) glds16(Bg + ko_ + p * pstr, dst_ + p * 2048); }
#define WRA_P(b)                                                               \
  { _Pragma("unroll")                                                          \
    for (int p = 0; p < 4; ++p) {                                              \
      s8v o_;                                                                  \
      o_[0] = f2bf_s(ar[p][0].x); o_[1] = f2bf_s(ar[p][0].y);                  \
      o_[2] = f2bf_s(ar[p][0].z); o_[3] = f2bf_s(ar[p][0].w);                  \
      o_[4] = f2bf_s(ar[p][1].x); o_[5] = f2bf_s(ar[p][1].y);                  \
      o_[6] = f2bf_s(ar[p][1].z); o_[7] = f2bf_s(ar[p][1].w);                  \
      *(s8v*)(SMEM + (b) * 16384 + t8 + p * 2048) = o_;                        \
    } }

  // prologue: A0 regs + B0 glds16; write A0; issue A1; B0 landed; barrier.
  LDA_P(0); SCHEDB();
  STB_P(0, 0); SCHEDB();
  WAITV(4); SCHEDB();        // A0 (8 oldest) done; B0 (4) in flight
  WRA_P(0); SCHEDB();
  LDA_P(1); SCHEDB();        // flight: B0(4) + A1(8)
  WAITV(8);                  // B0 landed; A1 stays in flight
  WAITL0();
  SBAR(); SCHEDB();

  for (int kt = 0; kt < 8; ++kt) {
    const int c = kt & 1;
    if (kt < 7) { STB_P(kt + 1, 1 - c); SCHEDB(); }   // flight: A(kt+1)8 + B(kt+1)4

    const unsigned cofs = (unsigned)(c << 15);
#pragma unroll
    for (int kk = 0; kk < 2; ++kk) {
      const unsigned kx = (unsigned)(kk << 6);
      s8v af[4], bf[4];
#pragma unroll
      for (int ii = 0; ii < 4; ++ii) af[ii] = dsr128((aoff[ii] ^ kx) + cofs);
#pragma unroll
      for (int j = 0; j < 4; ++j)   bf[j]  = dsr128((boff[j] ^ kx) + cofs);
      WAITL0();
      SCHEDB();
      __builtin_amdgcn_s_setprio(1);
#pragma unroll
      for (int ii = 0; ii < 4; ++ii)
#pragma unroll
        for (int j = 0; j < 4; ++j)
          acc[ii][j] = __builtin_amdgcn_mfma_f32_16x16x32_bf16(af[ii], bf[j], acc[ii][j], 0, 0, 0);
      __builtin_amdgcn_s_setprio(0);
    }

    if (kt < 7) {
      WAITV(4); SCHEDB();     // A(kt+1) regs done (B(kt+1) newest 4 remain)
      WRA_P(1 - c); SCHEDB(); // cvt + ds_write A(kt+1)
      if (kt < 6) { LDA_P(kt + 2); SCHEDB(); WAITV(8); }  // B(kt+1) done
      else        { WAITV(0); }                            // kt=6: drain B(7)
      WAITL0();
      SBAR(); SCHEDB();
    }
  }
#undef LDA_P
#undef STB_P
#undef WRA_P

  // ---- epilogue ----
  float bv[4];
#pragma unroll
  for (int j = 0; j < 4; ++j) bv[j] = bias[n0 + wn + j * 16 + l16];

  if (EPI == EPI_BIAS_T) {
#pragma unroll
    for (int i = 0; i < 4; ++i) {
#pragma unroll
      for (int j = 0; j < 4; ++j) {
        const int gn  = n0 + wn + j * 16 + l16;
        const int gmb = m0 + wm + i * 16 + quad * 4;
        const int bb = gmb >> 11, ssb = gmb & (S_LEN - 1);
        s4v o;
#pragma unroll
        for (int r = 0; r < 4; ++r) o[r] = f2bf_s(acc[i][j][r] + bv[j]);
        *(s4v*)&C[((size_t)bb * D_DIM + gn) * S_LEN + ssb] = o;
      }
    }
    return;
  }

  // EPI_BIAS: LDS transpose -> coalesced 16B row stores (C is [8192][512]).
  short* TB = SMEM;
  const int wbase = w * 2176;
#pragma unroll
  for (int ph = 0; ph < 2; ++ph) {
    __syncthreads();
#pragma unroll
    for (int ii = 0; ii < 2; ++ii) {
      const int i = ph * 2 + ii;
#pragma unroll
      for (int j = 0; j < 4; ++j) {
#pragma unroll
        for (int r = 0; r < 4; ++r)
          TB[wbase + (ii * 16 + quad * 4 + r) * 68 + j * 16 + l16] =
              f2bf_s(acc[i][j][r] + bv[j]);
      }
    }
    __syncthreads();
#pragma unroll
    for (int p = 0; p < 4; ++p) {
      const int row = p * 8 + (lane >> 3);
      const int cg  = lane & 7;
      const s8v vv = *(const s8v*)&TB[wbase + row * 68 + cg * 8];
      const int gm = m0 + wm + ph * 32 + row;
      const int gn = n0 + wn + cg * 8;
      *(s8v*)&C[(size_t)gm * D_DIM + gn] = vv;
    }
  }
}

// scores-F kernel: 1-D grid 544 (=8x68, XCD-bijective swizzle), tri tiles.
__global__ __launch_bounds__(256, 2) void gemm_scoresF(
    const short* __restrict__ A, const short* __restrict__ B, short* __restrict__ C,
    float* __restrict__ Z)
{
  __shared__ __align__(16) short SMEM[32768];   // 64 KB
  const int bid = blockIdx.x;
  const int bsw = (bid & 7) * 68 + (bid >> 3);  // consecutive bsw share one XCD
  const int bz  = bsw / 136;
  const int t   = bsw - bz * 136;
  int ti = (int)((sqrtf(8.0f * t + 1.0f) - 1.0f) * 0.5f);
  while ((ti + 1) * (ti + 2) / 2 <= t) ++ti;
  while (ti * (ti + 1) / 2 > t) --ti;
  const int tj = t - ti * (ti + 1) / 2;         // tj <= ti
  gemm_core<EPI_SCORES>(A + (size_t)bz * S_LEN * D_DIM, B + (size_t)bz * S_LEN * D_DIM,
                        C, nullptr, SMEM, S_LEN, D_DIM,
                        (size_t)bz * S_LEN * S_LEN, ti * 128, tj * 128, bz, Z);
}

// projections (fused fp32 cvt): 1-D grid 768 (=8x96, XCD-bijective swizzle).
__global__ __launch_bounds__(256, 2) void proj3(
    const float* __restrict__ qf, const float* __restrict__ kf, const float* __restrict__ vf,
    const short* __restrict__ Wqb, short* __restrict__ qp, short* __restrict__ kp,
    short* __restrict__ vpT,
    const float* __restrict__ x0, const float* __restrict__ x1, const float* __restrict__ x2)
{
  __shared__ __align__(16) short SMEM[32768];   // 64 KB
  const int bid = blockIdx.x;
  const int bsw = (bid & 7) * 96 + (bid >> 3);
  const int z   = bsw >> 8;
  const int rem = bsw & 255;
  const int m0  = (rem >> 2) * 128;
  const int n0  = (rem & 3) * 128;
  const float* A = (z == 0) ? qf : (z == 1) ? kf : vf;
  const short* B = Wqb + (size_t)z * 262144;
  short*       C = (z == 0) ? qp : (z == 1) ? kp : vpT;
  const float* bias = (z == 0) ? x0 : (z == 1) ? x1 : x2;
  if (z == 2)
    proj_core<EPI_BIAS_T>(A, B, C, bias, SMEM, m0, n0);
  else
    proj_core<EPI_BIAS>(A, B, C, bias, SMEM, m0, n0);
}

// out = F @ vpT'^T + T, 64x128 tiles, BK=64, K truncated at m0+64,
// triple-buffered (72 KB), prefetch distance 2 issued AFTER the barrier.
// Grid 512 1-D: h -> n0=(h&3)*128, bz=(h>>2)&3, zs=h>>4; co-resident pairs
// (h, h+256) get complementary niter (sum 33); long blocks dispatch first.
__global__ __launch_bounds__(256, 2) void gemm_outF(
    const short* __restrict__ F, const short* __restrict__ vpT,
    const float* __restrict__ Tv, float* __restrict__ out)
{
  __shared__ __align__(16) short SMEM[36864];   // 72 KB

  const int tid  = threadIdx.x;
  const int h    = blockIdx.x;
  const int n0   = (h & 3) * 128;
  const int bz   = (h >> 2) & 3;
  const int zs   = h >> 4;                      // 0..31
  const int mi   = (zs < 16) ? (31 - zs) : (zs - 16);
  const int m0   = mi * 64;

  const short* A = F   + (size_t)bz * S_LEN * S_LEN;
  const short* B = vpT + (size_t)bz * D_DIM * S_LEN;

  const int w    = tid >> 6;
  const int lane = tid & 63;
  const int quad = lane >> 4;
  const int l16  = lane & 15;
  const int wm   = (w >> 1) * 32;
  const int wn   = (w & 1) * 64;

  const int strow = tid >> 3;
  const int gl = ((tid & 7) ^ (strow & 7)) * 8;

  f4v acc[2][4];
#pragma unroll
  for (int i = 0; i < 2; ++i)
#pragma unroll
    for (int j = 0; j < 4; ++j)
#pragma unroll
      for (int r = 0; r < 4; ++r) acc[i][j][r] = 0.0f;

  const short* Ag = A + (size_t)(m0 + strow) * S_LEN + gl;
  const short* Bg = B + (size_t)(n0 + strow) * S_LEN + gl;
  const size_t pstr = (size_t)32 * S_LEN;
  const int t8 = tid * 8;
  const int swq = l16 & 7;

  const unsigned base = lds_addr(SMEM);
  unsigned aoff[2], boff[4];
#pragma unroll
  for (int ii = 0; ii < 2; ++ii)
    aoff[ii] = base + (unsigned)((wm + ii * 16 + l16) * 128 + ((quad ^ swq) * 16));
#pragma unroll
  for (int j = 0; j < 4; ++j)
    boff[j] = base + 8192u + (unsigned)((wn + j * 16 + l16) * 128 + ((quad ^ swq) * 16));

  const int niter = mi + 1;   // K runs 0 .. m0+64

  // preload tiles 0,1 into bufs 0,1 (6 loads each: A x2, B x4)
#pragma unroll
  for (int pre = 0; pre < 2; ++pre) {
    short* dst = SMEM + pre * 12288 + t8;
    const int k0 = pre << 6;
#pragma unroll
    for (int p = 0; p < 2; ++p) glds16(Ag + k0 + p * pstr, dst + p * 2048);
#pragma unroll
    for (int p = 0; p < 4; ++p) glds16(Bg + k0 + p * pstr, dst + 4096 + p * 2048);
  }

  int cbuf = 0;
  for (int i = 0; i < niter; ++i) {
    if (i + 1 < niter) { WAITV(6); } else { WAITV(0); }   // tile i landed
    SBAR();
    SCHEDB();

    if (i + 2 < niter) {          // issue i+2 into the buffer read at i-1
      int nb = cbuf + 2; if (nb >= 3) nb -= 3;
      const int k2 = (i + 2) << 6;
      short* dst = SMEM + nb * 12288 + t8;
#pragma unroll
      for (int p = 0; p < 2; ++p) glds16(Ag + k2 + p * pstr, dst + p * 2048);
#pragma unroll
      for (int p = 0; p < 4; ++p) glds16(Bg + k2 + p * pstr, dst + 4096 + p * 2048);
      SCHEDB();
    }

    const unsigned cofs = (unsigned)(cbuf * 24576);
    cbuf = (cbuf == 2) ? 0 : cbuf + 1;
#pragma unroll
    for (int kk = 0; kk < 2; ++kk) {
      const unsigned kx = (unsigned)(kk << 6);
      s8v af[2], bf[4];
#pragma unroll
      for (int ii = 0; ii < 2; ++ii) af[ii] = dsr128((aoff[ii] ^ kx) + cofs);
#pragma unroll
      for (int j = 0; j < 4; ++j)   bf[j]  = dsr128((boff[j] ^ kx) + cofs);
      WAITL0();
      SCHEDB();
      __builtin_amdgcn_s_setprio(1);
#pragma unroll
      for (int ii = 0; ii < 2; ++ii)
#pragma unroll
        for (int j = 0; j < 4; ++j)
          acc[ii][j] = __builtin_amdgcn_mfma_f32_16x16x32_bf16(af[ii], bf[j], acc[ii][j], 0, 0, 0);
      __builtin_amdgcn_s_setprio(0);
    }
  }

  float* Cf = out + (size_t)bz * S_LEN * D_DIM;
#pragma unroll
  for (int i = 0; i < 2; ++i) {
#pragma unroll
    for (int j = 0; j < 4; ++j) {
      const int gn = n0 + wn + j * 16 + l16;
      const float tvn = Tv[(bz << 9) + gn];
#pragma unroll
      for (int r = 0; r < 4; ++r) {
        const int gm = m0 + wm + i * 16 + quad * 4 + r;
        Cf[(size_t)gm * D_DIM + gn] = acc[i][j][r] + tvn;
      }
    }
  }
}

// fp32 -> bf16 for the three weight matrices; also zeroes ZF.
__global__ __launch_bounds__(256) void cvt_w(
    const float* __restrict__ wq, const float* __restrict__ wk, const float* __restrict__ wv,
    short* __restrict__ Wqb, float* __restrict__ ZF)
{
  const int y = blockIdx.y;
  const float* s = (y == 0) ? wq : (y == 1) ? wk : wv;
  short* d = Wqb + (size_t)y * 262144;
  const int gid = blockIdx.x * 256 + threadIdx.x;
  const int i = gid * 8;
  const float4 f0 = *(const float4*)(s + i);
  const float4 f1 = *(const float4*)(s + i + 4);
  s8v o;
  o[0] = f2bf_s(f0.x); o[1] = f2bf_s(f0.y); o[2] = f2bf_s(f0.z); o[3] = f2bf_s(f0.w);
  o[4] = f2bf_s(f1.x); o[5] = f2bf_s(f1.y); o[6] = f2bf_s(f1.z); o[7] = f2bf_s(f1.w);
  *(s8v*)(d + i) = o;
  if (y == 0 && gid < 8192) ZF[gid] = 0.0f;
}

// block per (b,d): vpT[b][d][k] /= (2048+ZF[b][k]); Tv[b,d] = sum_k (fp32)
__global__ __launch_bounds__(256) void scale_vpt_T(
    short* __restrict__ vpT, const float* __restrict__ ZF, float* __restrict__ Tv)
{
  __shared__ float red[4];
  const int b = blockIdx.y, d = blockIdx.x, tid = threadIdx.x;
  const size_t rowbase = ((size_t)(b * D_DIM + d)) * S_LEN;
  const float* zf = ZF + (b << 11);
  const int k0 = tid * 8;

  s8v v = *(s8v*)&vpT[rowbase + k0];
  float s = 0.0f;
#pragma unroll
  for (int i = 0; i < 8; ++i) {
    const float w = bf2f_s(v[i]) / (2048.0f + zf[k0 + i]);
    s += w;
    v[i] = f2bf_s(w);
  }
  *(s8v*)&vpT[rowbase + k0] = v;

#pragma unroll
  for (int off = 32; off >= 1; off >>= 1) s += __shfl_xor(s, off, 64);
  if ((tid & 63) == 0) red[tid >> 6] = s;
  __syncthreads();
  if (tid == 0) Tv[(b << 9) + d] = red[0] + red[1] + red[2] + red[3];
}

extern "C" void kernel_launch(void* const* d_in, const int* in_sizes, int n_in,
                              void* d_out, int out_size, void* d_ws, size_t ws_size,
                              hipStream_t stream) {
  const float* q   = (const float*)d_in[0];
  const float* k   = (const float*)d_in[1];
  const float* v   = (const float*)d_in[2];
  const float* WQw = (const float*)d_in[3];
  const float* WQb = (const float*)d_in[4];
  const float* WKw = (const float*)d_in[5];
  const float* WKb = (const float*)d_in[6];
  const float* WVw = (const float*)d_in[7];
  const float* WVb = (const float*)d_in[8];

  char* ws = (char*)d_ws;
  // F occupies [0,32M); Wqb lives above it (weights must survive proj)
  short* F   = (short*)(ws);                 // 32 MB  [4][2048][2048] (lower tiles only)
  short* Wqb = (short*)(ws + 25165824);      // 3x 512 KB contiguous (dead before F's upper region is written? F rows only lower-tri tiles; region is within F but only read before scoresF writes it -- kept as in R4b layout)
  short* qp  = (short*)(ws + 33554432);      //  8 MB  [4][2048][512]
  short* kp  = (short*)(ws + 41943040);      //  8 MB
  short* vpT = (short*)(ws + 50331648);      //  8 MB  [4][512][2048]
  float* ZF  = (float*)(ws + 58720256);      // 32 KB  [4][2048]
  float* Tv  = (float*)(ws + 58753024);      //  8 KB  [4][512]

  const dim3 blk(256);

  // weights fp32->bf16 + ZF zero (one small launch)
  cvt_w<<<dim3(128, 3), blk, 0, stream>>>(WQw, WKw, WVw, Wqb, ZF);

  // projections with fused input conversion: 768 blocks, XCD-swizzled
  proj3<<<dim3(768), blk, 0, stream>>>(
      q, k, v, Wqb, qp, kp, vpT, WQb, WKb, WVb);

  // F = expm1(scale*qp@kp^T) lower-tri tiles + fused ZF colsum: 544 blocks
  gemm_scoresF<<<dim3(544), blk, 0, stream>>>(qp, kp, F, ZF);

  // vpT' = vpT/(2048+ZF); Tv = rowsum(vpT')
  scale_vpt_T<<<dim3(512, 4), blk, 0, stream>>>(vpT, ZF, Tv);

  // out = F @ vpT'^T + Tv: 64x128 tiles, K truncated at m0+64, balanced pairs
  gemm_outF<<<dim3(512), blk, 0, stream>>>(F, vpT, Tv, (float*)d_out);
}

// Round 9
// 167.646 us; speedup vs baseline: 1.1547x; 1.0820x over previous
//
#include <hip/hip_runtime.h>
#include <hip/hip_bf16.h>

// B=4, S=2048, D=512. fp32 in/out, bf16 MFMA internals.
// Key identity: multiplicative causal mask => E = 1 + F, F = expm1(scale*s) on
// the lower triangle (q>=k), 0 above. Then
//   out  = F @ vp'  +  T,   T[b,d] = sum_k vp'[b,k,d]
//   Z[k] = 2048 + colsum(F)
// Pipeline: cvt_all(+ZF0) | proj3 | scoresF | scaleT | outF
//
// R8: base = R4b (best, 168.5us; glds16 staging — both reg-staging variants
//     R6/R7 regressed). New: round-quantization fix. Capacity = 512 blocks
//     (2/CU, 64KB LDS). proj was 768 equal blocks -> 2 rounds (ideal 1.5);
//     scores 544 -> 2 rounds (ideal 1.06). gemm_core is now templated on MW
//     (M-fragments/wave): MW=4 -> 128x128 tile, MW=2 -> 64x128 half-tile
//     (T/2). proj = 512 fulls (z=0,1) + 512 halves (z=2) -> 1.5T.
//     scores = 480 off-diag fulls + 128 diagonal halves -> ~1.5T.
//     ERRATA: R3's 4.3M bank conflicts were the scalar ds_write_b16 epilogue
//     transpose (harmless), not the K-loop. ZF memset folded into cvt_all.

#define S_LEN 2048
#define D_DIM 512
#define SCALE_F 0.044194173824159216f  // 1/sqrt(512)

typedef __attribute__((ext_vector_type(8))) short s8v;   // 8 bf16 = 4 VGPRs
typedef __attribute__((ext_vector_type(4))) short s4v;   // 4 bf16 = 8 B
typedef __attribute__((ext_vector_type(4))) float f4v;   // MFMA accumulator

enum { EPI_BIAS = 0, EPI_BIAS_T = 1, EPI_SCORES = 2 };

#define SBAR()    __builtin_amdgcn_s_barrier()
#define SCHEDB()  __builtin_amdgcn_sched_barrier(0)
#define WAITV(n)  asm volatile("s_waitcnt vmcnt(" #n ")")
#define WAITL0()  asm volatile("s_waitcnt lgkmcnt(0)")

__device__ __forceinline__ short f2bf_s(float f) {
  union { __hip_bfloat16 b; short s; } u; u.b = __float2bfloat16(f); return u.s;
}
__device__ __forceinline__ float bf2f_s(short h) {
  union { short s; __hip_bfloat16 b; } u; u.s = h; return __bfloat162float(u.b);
}

__device__ __forceinline__ void glds16(const short* g, short* l) {
  __builtin_amdgcn_global_load_lds((const __attribute__((address_space(1))) void*)g,
                                   (__attribute__((address_space(3))) void*)l, 16, 0, 0);
}

// LDS byte offset of a __shared__-derived pointer (addrspace(3) is 32-bit).
__device__ __forceinline__ unsigned lds_addr(const short* p) {
  return (unsigned)(unsigned long long)(const __attribute__((address_space(3))) short*)p;
}

// Inline-asm ds_read_b128: keeps the counted WAITV authoritative. MUST be
// followed by lgkmcnt(0)+SCHEDB before any consumer (rule 18).
__device__ __forceinline__ s8v dsr128(unsigned a) {
  s8v r;
  asm volatile("ds_read_b128 %0, %1" : "=&v"(r) : "v"(a));
  return r;
}

// ---------------------------------------------------------------------------
// Core NT GEMM, (MW*32)x128 tile at (m0,n0), BK=64, LDS double buffer.
// MW=4: 128x128 tile, 32 KB/buf (64 KB total), 8 loads/tile, WAITV(8).
// MW=2:  64x128 tile, 24 KB/buf (48 KB total), 6 loads/tile, WAITV(6).
// Per iter: stage i+1 -> counted WAITV (tile i landed, i+1 in flight) ->
// SBAR -> 2 phases {asm ds_read, lgkmcnt(0), setprio(1), MFMA} -> SBAR.
template <int MW, int EPI>
__device__ __forceinline__ void gemm_core(
    const short* __restrict__ A, const short* __restrict__ B,
    short* __restrict__ C, const float* __restrict__ bias,
    short* SMEM, int N, int K, size_t sCz, int m0, int n0, int bz,
    float* __restrict__ Z)
{
  constexpr int ABYTE  = MW * 4096;        // A bytes per buffer
  constexpr int BUFB   = ABYTE + 16384;    // buffer stride in bytes

  const int tid  = threadIdx.x;
  const int w    = tid >> 6;
  const int lane = tid & 63;
  const int quad = lane >> 4;
  const int l16  = lane & 15;
  const int wm   = (w >> 1) * (MW * 16);
  const int wn   = (w & 1) * 64;

  const int strow = tid >> 3;                         // 0..31
  const int gl = ((tid & 7) ^ (strow & 7)) * 8;       // XOR column-octet swizzle

  f4v acc[MW][4];
#pragma unroll
  for (int i = 0; i < MW; ++i)
#pragma unroll
    for (int j = 0; j < 4; ++j)
#pragma unroll
      for (int r = 0; r < 4; ++r) acc[i][j][r] = 0.0f;

  const short* Ag = A + (size_t)(m0 + strow) * K + gl;
  const short* Bg = B + (size_t)(n0 + strow) * K + gl;
  const size_t pstr = (size_t)32 * K;
  const int t8 = tid * 8;
  const int swq = l16 & 7;

  const unsigned base = lds_addr(SMEM);
  unsigned aoff[MW], boff[4];
#pragma unroll
  for (int ii = 0; ii < MW; ++ii)
    aoff[ii] = base + (unsigned)((wm + ii * 16 + l16) * 128 + ((quad ^ swq) * 16));
#pragma unroll
  for (int j = 0; j < 4; ++j)
    boff[j] = base + (unsigned)ABYTE + (unsigned)((wn + j * 16 + l16) * 128 + ((quad ^ swq) * 16));

  const int niter = K >> 6;

  // prologue: tile0 -> buf0
#pragma unroll
  for (int p = 0; p < MW; ++p) glds16(Ag + p * pstr, SMEM + t8 + p * 2048);
#pragma unroll
  for (int p = 0; p < 4; ++p) glds16(Bg + p * pstr, SMEM + ABYTE / 2 + t8 + p * 2048);

  for (int i = 0; i < niter; ++i) {
    const int c = i & 1;
    if (i + 1 < niter) {
      const int k1 = (i + 1) << 6;
      short* dA = SMEM + (1 - c) * (BUFB / 2) + t8;
#pragma unroll
      for (int p = 0; p < MW; ++p) glds16(Ag + k1 + p * pstr, dA + p * 2048);
#pragma unroll
      for (int p = 0; p < 4; ++p) glds16(Bg + k1 + p * pstr, dA + ABYTE / 2 + p * 2048);
      SCHEDB();
      if constexpr (MW == 4) { WAITV(8); } else { WAITV(6); }
    } else {
      WAITV(0);
    }
    SBAR();
    SCHEDB();

    const unsigned cofs = (unsigned)(c * BUFB);
#pragma unroll
    for (int kk = 0; kk < 2; ++kk) {
      const unsigned kx = (unsigned)(kk << 6);
      s8v af[MW], bf[4];
#pragma unroll
      for (int ii = 0; ii < MW; ++ii) af[ii] = dsr128((aoff[ii] ^ kx) + cofs);
#pragma unroll
      for (int j = 0; j < 4; ++j)    bf[j]  = dsr128((boff[j] ^ kx) + cofs);
      WAITL0();
      SCHEDB();
      __builtin_amdgcn_s_setprio(1);
#pragma unroll
      for (int ii = 0; ii < MW; ++ii)
#pragma unroll
        for (int j = 0; j < 4; ++j)
          acc[ii][j] = __builtin_amdgcn_mfma_f32_16x16x32_bf16(af[ii], bf[j], acc[ii][j], 0, 0, 0);
      __builtin_amdgcn_s_setprio(0);
    }
    SBAR();              // buf c free for next iter's prefetch
  }

  // ---- epilogue ----
  float bv[4];
  if (EPI == EPI_BIAS || EPI == EPI_BIAS_T) {
#pragma unroll
    for (int j = 0; j < 4; ++j) bv[j] = bias[n0 + wn + j * 16 + l16];
  }

  if (EPI == EPI_BIAS_T) {
#pragma unroll
    for (int i = 0; i < MW; ++i) {
#pragma unroll
      for (int j = 0; j < 4; ++j) {
        const int gn  = n0 + wn + j * 16 + l16;
        const int gmb = m0 + wm + i * 16 + quad * 4;
        const int bb = gmb >> 11, ssb = gmb & (S_LEN - 1);
        s4v o;
#pragma unroll
        for (int r = 0; r < 4; ++r) o[r] = f2bf_s(acc[i][j][r] + bv[j]);
        *(s4v*)&C[((size_t)bb * D_DIM + gn) * S_LEN + ssb] = o;
      }
    }
    return;
  }

  // EPI_BIAS / EPI_SCORES: LDS transpose -> coalesced 16B row stores.
  short* TB = SMEM;                 // 4 waves x 2176 shorts (32 rows x stride 68)
  const int wbase = w * 2176;
  float csum[4] = {0.f, 0.f, 0.f, 0.f};

#pragma unroll
  for (int ph = 0; ph < MW / 2; ++ph) {
    __syncthreads();
#pragma unroll
    for (int ii = 0; ii < 2; ++ii) {
      const int i = ph * 2 + ii;
#pragma unroll
      for (int j = 0; j < 4; ++j) {
        const int gn = n0 + wn + j * 16 + l16;
#pragma unroll
        for (int r = 0; r < 4; ++r) {
          short o;
          if (EPI == EPI_SCORES) {
            const int gm = m0 + wm + i * 16 + quad * 4 + r;
            const float f = (gm >= gn) ? (__expf(acc[i][j][r] * SCALE_F) - 1.0f) : 0.0f;
            csum[j] += f;
            o = f2bf_s(f);
          } else {
            o = f2bf_s(acc[i][j][r] + bv[j]);
          }
          TB[wbase + (ii * 16 + quad * 4 + r) * 68 + j * 16 + l16] = o;
        }
      }
    }
    __syncthreads();
#pragma unroll
    for (int p = 0; p < 4; ++p) {
      const int row = p * 8 + (lane >> 3);   // 0..31
      const int cg  = lane & 7;
      const s8v vv = *(const s8v*)&TB[wbase + row * 68 + cg * 8];
      const int gm = m0 + wm + ph * 32 + row;
      const int gn = n0 + wn + cg * 8;
      *(s8v*)&C[sCz + (size_t)gm * N + gn] = vv;
    }
  }

  if (EPI == EPI_SCORES) {
#pragma unroll
    for (int j = 0; j < 4; ++j) {
      float cs = csum[j];
      cs += __shfl_xor(cs, 16, 64);
      cs += __shfl_xor(cs, 32, 64);
      if (quad == 0) atomicAdd(&Z[(bz << 11) + n0 + wn + j * 16 + l16], cs);
    }
  }
}

// scores-F kernel: grid 608 = 480 off-diagonal full tiles (dispatched first)
// + 128 diagonal half-tiles (64x128, T/2 — backfill the tail round).
__global__ __launch_bounds__(256, 2) void gemm_scoresF(
    const short* __restrict__ A, const short* __restrict__ B, short* __restrict__ C,
    float* __restrict__ Z)
{
  __shared__ __align__(16) short SMEM[32768];   // 64 KB
  const int bid = blockIdx.x;
  if (bid < 480) {
    // off-diagonal lower tiles (ti > tj): 120 per batch
    const int fsw = (bid & 7) * 60 + (bid >> 3);  // XCD-bijective (480 = 8x60)
    const int bz  = fsw / 120;
    const int tp  = fsw - bz * 120;               // t' = ti(ti-1)/2 + tj
    int ti = (int)((1.0f + sqrtf(1.0f + 8.0f * tp)) * 0.5f);
    while (ti * (ti - 1) / 2 > tp) --ti;
    while ((ti + 1) * ti / 2 <= tp) ++ti;
    const int tj = tp - ti * (ti - 1) / 2;        // tj < ti
    gemm_core<4, EPI_SCORES>(A + (size_t)bz * S_LEN * D_DIM, B + (size_t)bz * S_LEN * D_DIM,
                             C, nullptr, SMEM, S_LEN, D_DIM,
                             (size_t)bz * S_LEN * S_LEN, ti * 128, tj * 128, bz, Z);
  } else {
    // diagonal tiles split into two 64-row halves: 16 diag x 2 x 4 batches
    const int d   = bid - 480;
    const int dsw = (d & 7) * 16 + (d >> 3);      // XCD-bijective (128 = 8x16)
    const int c   = dsw >> 1;                     // 0..63
    const int bz  = c >> 4;
    const int ti  = c & 15;
    const int hf  = dsw & 1;
    gemm_core<2, EPI_SCORES>(A + (size_t)bz * S_LEN * D_DIM, B + (size_t)bz * S_LEN * D_DIM,
                             C, nullptr, SMEM, S_LEN, D_DIM,
                             (size_t)bz * S_LEN * S_LEN, ti * 128 + hf * 64, ti * 128, bz, Z);
  }
}

// projections: grid 1024 = 512 full tiles (z=0:qp, z=1:kp; fill capacity
// exactly) + 512 half-tiles (z=2: vpT, 64-row, T/2 — backfill round 2).
__global__ __launch_bounds__(256, 2) void proj3(
    const short* __restrict__ a0, const short* __restrict__ a1, const short* __restrict__ a2,
    const short* __restrict__ b0, const short* __restrict__ b1, const short* __restrict__ b2,
    short* __restrict__ c0, short* __restrict__ c1, short* __restrict__ c2,
    const float* __restrict__ x0, const float* __restrict__ x1, const float* __restrict__ x2)
{
  __shared__ __align__(16) short SMEM[32768];   // 64 KB
  const int bid = blockIdx.x;
  if (bid < 512) {
    const int bsw = (bid & 7) * 64 + (bid >> 3);  // XCD-bijective (512 = 8x64)
    const int z   = bsw >> 8;                     // 0 or 1
    const int rem = bsw & 255;
    const int m0  = (rem >> 2) * 128;
    const int n0  = (rem & 3) * 128;
    const short* A = z ? a1 : a0;
    const short* B = z ? b1 : b0;
    short*       C = z ? c1 : c0;
    const float* bias = z ? x1 : x0;
    gemm_core<4, EPI_BIAS>(A, B, C, bias, SMEM, D_DIM, D_DIM, 0, m0, n0, 0, nullptr);
  } else {
    const int h   = bid - 512;
    const int hsw = (h & 7) * 64 + (h >> 3);      // XCD-bijective (512 = 8x64)
    const int m0  = (hsw >> 2) * 64;
    const int n0  = (hsw & 3) * 128;
    gemm_core<2, EPI_BIAS_T>(a2, b2, c2, x2, SMEM, D_DIM, D_DIM, 0, m0, n0, 0, nullptr);
  }
}

// out = F @ vpT'^T + T, 64x128 tiles, BK=64, K truncated at m0+64,
// triple-buffered (72 KB), prefetch distance 2 issued AFTER the barrier.
// Grid 512 1-D: h -> n0=(h&3)*128, bz=(h>>2)&3, zs=h>>4; co-resident pairs
// (h, h+256) get complementary niter (sum 33); long blocks dispatch first.
__global__ __launch_bounds__(256, 2) void gemm_outF(
    const short* __restrict__ F, const short* __restrict__ vpT,
    const float* __restrict__ Tv, float* __restrict__ out)
{
  __shared__ __align__(16) short SMEM[36864];   // 72 KB

  const int tid  = threadIdx.x;
  const int h    = blockIdx.x;
  const int n0   = (h & 3) * 128;
  const int bz   = (h >> 2) & 3;
  const int zs   = h >> 4;                      // 0..31
  const int mi   = (zs < 16) ? (31 - zs) : (zs - 16);
  const int m0   = mi * 64;

  const short* A = F   + (size_t)bz * S_LEN * S_LEN;
  const short* B = vpT + (size_t)bz * D_DIM * S_LEN;

  const int w    = tid >> 6;
  const int lane = tid & 63;
  const int quad = lane >> 4;
  const int l16  = lane & 15;
  const int wm   = (w >> 1) * 32;
  const int wn   = (w & 1) * 64;

  const int strow = tid >> 3;
  const int gl = ((tid & 7) ^ (strow & 7)) * 8;

  f4v acc[2][4];
#pragma unroll
  for (int i = 0; i < 2; ++i)
#pragma unroll
    for (int j = 0; j < 4; ++j)
#pragma unroll
      for (int r = 0; r < 4; ++r) acc[i][j][r] = 0.0f;

  const short* Ag = A + (size_t)(m0 + strow) * S_LEN + gl;
  const short* Bg = B + (size_t)(n0 + strow) * S_LEN + gl;
  const size_t pstr = (size_t)32 * S_LEN;
  const int t8 = tid * 8;
  const int swq = l16 & 7;

  const unsigned base = lds_addr(SMEM);
  unsigned aoff[2], boff[4];
#pragma unroll
  for (int ii = 0; ii < 2; ++ii)
    aoff[ii] = base + (unsigned)((wm + ii * 16 + l16) * 128 + ((quad ^ swq) * 16));
#pragma unroll
  for (int j = 0; j < 4; ++j)
    boff[j] = base + 8192u + (unsigned)((wn + j * 16 + l16) * 128 + ((quad ^ swq) * 16));

  const int niter = mi + 1;   // K runs 0 .. m0+64

  // preload tiles 0,1 into bufs 0,1 (6 loads each: A x2, B x4)
#pragma unroll
  for (int pre = 0; pre < 2; ++pre) {
    short* dst = SMEM + pre * 12288 + t8;
    const int k0 = pre << 6;
#pragma unroll
    for (int p = 0; p < 2; ++p) glds16(Ag + k0 + p * pstr, dst + p * 2048);
#pragma unroll
    for (int p = 0; p < 4; ++p) glds16(Bg + k0 + p * pstr, dst + 4096 + p * 2048);
  }

  int cbuf = 0;
  for (int i = 0; i < niter; ++i) {
    if (i + 1 < niter) { WAITV(6); } else { WAITV(0); }   // tile i landed
    SBAR();
    SCHEDB();

    if (i + 2 < niter) {          // issue i+2 into the buffer read at i-1
      int nb = cbuf + 2; if (nb >= 3) nb -= 3;
      const int k2 = (i + 2) << 6;
      short* dst = SMEM + nb * 12288 + t8;
#pragma unroll
      for (int p = 0; p < 2; ++p) glds16(Ag + k2 + p * pstr, dst + p * 2048);
#pragma unroll
      for (int p = 0; p < 4; ++p) glds16(Bg + k2 + p * pstr, dst + 4096 + p * 2048);
      SCHEDB();
    }

    const unsigned cofs = (unsigned)(cbuf * 24576);
    cbuf = (cbuf == 2) ? 0 : cbuf + 1;
#pragma unroll
    for (int kk = 0; kk < 2; ++kk) {
      const unsigned kx = (unsigned)(kk << 6);
      s8v af[2], bf[4];
#pragma unroll
      for (int ii = 0; ii < 2; ++ii) af[ii] = dsr128((aoff[ii] ^ kx) + cofs);
#pragma unroll
      for (int j = 0; j < 4; ++j)   bf[j]  = dsr128((boff[j] ^ kx) + cofs);
      WAITL0();
      SCHEDB();
      __builtin_amdgcn_s_setprio(1);
#pragma unroll
      for (int ii = 0; ii < 2; ++ii)
#pragma unroll
        for (int j = 0; j < 4; ++j)
          acc[ii][j] = __builtin_amdgcn_mfma_f32_16x16x32_bf16(af[ii], bf[j], acc[ii][j], 0, 0, 0);
      __builtin_amdgcn_s_setprio(0);
    }
  }

  float* Cf = out + (size_t)bz * S_LEN * D_DIM;
#pragma unroll
  for (int i = 0; i < 2; ++i) {
#pragma unroll
    for (int j = 0; j < 4; ++j) {
      const int gn = n0 + wn + j * 16 + l16;
      const float tvn = Tv[(bz << 9) + gn];
#pragma unroll
      for (int r = 0; r < 4; ++r) {
        const int gm = m0 + wm + i * 16 + quad * 4 + r;
        Cf[(size_t)gm * D_DIM + gn] = acc[i][j][r] + tvn;
      }
    }
  }
}

// fp32 -> bf16, one launch for data (x<2048) and weights (x>=2048); zeroes ZF.
__global__ __launch_bounds__(256) void cvt_all(
    const float* __restrict__ q, const float* __restrict__ k, const float* __restrict__ v,
    const float* __restrict__ wq, const float* __restrict__ wk, const float* __restrict__ wv,
    short* __restrict__ qb, short* __restrict__ Wqb, float* __restrict__ ZF)
{
  const int y = blockIdx.y;
  const float* s; short* d; int i;
  if (blockIdx.x < 2048) {
    s = (y == 0) ? q : (y == 1) ? k : v;
    d = qb + (size_t)y * 4194304;
    i = (blockIdx.x * 256 + threadIdx.x) * 8;
    if (y == 0) {
      const int gid = blockIdx.x * 256 + threadIdx.x;
      if (gid < 8192) ZF[gid] = 0.0f;
    }
  } else {
    s = (y == 0) ? wq : (y == 1) ? wk : wv;
    d = Wqb + (size_t)y * 262144;
    i = ((int)(blockIdx.x - 2048) * 256 + threadIdx.x) * 8;
  }
  const float4 f0 = *(const float4*)(s + i);
  const float4 f1 = *(const float4*)(s + i + 4);
  s8v o;
  o[0] = f2bf_s(f0.x); o[1] = f2bf_s(f0.y); o[2] = f2bf_s(f0.z); o[3] = f2bf_s(f0.w);
  o[4] = f2bf_s(f1.x); o[5] = f2bf_s(f1.y); o[6] = f2bf_s(f1.z); o[7] = f2bf_s(f1.w);
  *(s8v*)(d + i) = o;
}

// block per (b,d): vpT[b][d][k] /= (2048+ZF[b][k]); Tv[b,d] = sum_k (fp32)
__global__ __launch_bounds__(256) void scale_vpt_T(
    short* __restrict__ vpT, const float* __restrict__ ZF, float* __restrict__ Tv)
{
  __shared__ float red[4];
  const int b = blockIdx.y, d = blockIdx.x, tid = threadIdx.x;
  const size_t rowbase = ((size_t)(b * D_DIM + d)) * S_LEN;
  const float* zf = ZF + (b << 11);
  const int k0 = tid * 8;

  s8v v = *(s8v*)&vpT[rowbase + k0];
  float s = 0.0f;
#pragma unroll
  for (int i = 0; i < 8; ++i) {
    const float w = bf2f_s(v[i]) / (2048.0f + zf[k0 + i]);
    s += w;
    v[i] = f2bf_s(w);
  }
  *(s8v*)&vpT[rowbase + k0] = v;

#pragma unroll
  for (int off = 32; off >= 1; off >>= 1) s += __shfl_xor(s, off, 64);
  if ((tid & 63) == 0) red[tid >> 6] = s;
  __syncthreads();
  if (tid == 0) Tv[(b << 9) + d] = red[0] + red[1] + red[2] + red[3];
}

extern "C" void kernel_launch(void* const* d_in, const int* in_sizes, int n_in,
                              void* d_out, int out_size, void* d_ws, size_t ws_size,
                              hipStream_t stream) {
  const float* q   = (const float*)d_in[0];
  const float* k   = (const float*)d_in[1];
  const float* v   = (const float*)d_in[2];
  const float* WQw = (const float*)d_in[3];
  const float* WQb = (const float*)d_in[4];
  const float* WKw = (const float*)d_in[5];
  const float* WKb = (const float*)d_in[6];
  const float* WVw = (const float*)d_in[7];
  const float* WVb = (const float*)d_in[8];

  char* ws = (char*)d_ws;
  // F occupies [0,32M); bf16 input/weight copies alias its head (dead before F written)
  short* F   = (short*)(ws);                 // 32 MB  [4][2048][2048] (lower tiles only)
  short* qb  = (short*)(ws);                 //  8 MB  (qb,kb,vb contiguous)
  short* Wqb = (short*)(ws + 25165824);      // 3x 512 KB contiguous
  short* qp  = (short*)(ws + 33554432);      //  8 MB  [4][2048][512]
  short* kp  = (short*)(ws + 41943040);      //  8 MB
  short* vpT = (short*)(ws + 50331648);      //  8 MB  [4][512][2048]
  float* ZF  = (float*)(ws + 58720256);      // 32 KB  [4][2048]
  float* Tv  = (float*)(ws + 58753024);      //  8 KB  [4][512]
  short* kb  = qb + 4194304;
  short* vb  = qb + 8388608;
  short* Wkb = Wqb + 262144;
  short* Wvb = Wqb + 524288;

  const dim3 blk(256);

  cvt_all<<<dim3(2176, 3), blk, 0, stream>>>(q, k, v, WQw, WKw, WVw, qb, Wqb, ZF);

  // projections: 512 full tiles (qp,kp) + 512 vpT half-tiles -> 1.5 rounds
  proj3<<<dim3(1024), blk, 0, stream>>>(
      qb, kb, vb, Wqb, Wkb, Wvb, qp, kp, vpT, WQb, WKb, WVb);

  // F tiles: 480 off-diag fulls + 128 diagonal halves -> ~1.5 rounds
  gemm_scoresF<<<dim3(608), blk, 0, stream>>>(qp, kp, F, ZF);

  // vpT' = vpT/(2048+ZF); Tv = rowsum(vpT')
  scale_vpt_T<<<dim3(512, 4), blk, 0, stream>>>(vpT, ZF, Tv);

  // out = F @ vpT'^T + Tv: 64x128 tiles, K truncated at m0+64, balanced pairs
  gemm_outF<<<dim3(512), blk, 0, stream>>>(F, vpT, Tv, (float*)d_out);
}

// Round 11
// 164.426 us; speedup vs baseline: 1.1773x; 1.0196x over previous
//
#include <hip/hip_runtime.h>
#include <hip/hip_bf16.h>

// B=4, S=2048, D=512. fp32 in/out, bf16 MFMA internals.
// Key identity: multiplicative causal mask => E = 1 + F, F = expm1(scale*s) on
// the lower triangle (q>=k), 0 above. Then
//   out  = F @ vp'  +  T,   T[b,d] = sum_k vp'[b,k,d]
//   Z[k] = 2048 + colsum(F)
// Pipeline: cvt_all(+ZF0) | proj_qk | scores_projv | scaleT | outF
//
// R10: R9's dependency-aware fusion (proj_qk = 512 tiles = 1 round;
//      scores(544) + vpT-projection(256) fused = 2 rounds) had a workspace
//      RACE: vb/Wvb aliased F's region, and fused scores tiles (bz=2,3)
//      overwrote them while vpT tiles were still reading -> absmax 4e-3 FAIL.
//      Fix: vb and Wvb now live in d_out scratch (out[0,8MB) / out[8,8.5MB)),
//      which nothing touches until outF fully overwrites it in the last
//      phase. qb/kb/Wqb/Wkb still alias F (dead before any F write).
//      All GEMM cores byte-identical to R4b/R9.

#define S_LEN 2048
#define D_DIM 512
#define SCALE_F 0.044194173824159216f  // 1/sqrt(512)

typedef __attribute__((ext_vector_type(8))) short s8v;   // 8 bf16 = 4 VGPRs
typedef __attribute__((ext_vector_type(4))) short s4v;   // 4 bf16 = 8 B
typedef __attribute__((ext_vector_type(4))) float f4v;   // MFMA accumulator

enum { EPI_BIAS = 0, EPI_BIAS_T = 1, EPI_SCORES = 2 };

#define SBAR()    __builtin_amdgcn_s_barrier()
#define SCHEDB()  __builtin_amdgcn_sched_barrier(0)
#define WAITV(n)  asm volatile("s_waitcnt vmcnt(" #n ")")
#define WAITL0()  asm volatile("s_waitcnt lgkmcnt(0)")

__device__ __forceinline__ short f2bf_s(float f) {
  union { __hip_bfloat16 b; short s; } u; u.b = __float2bfloat16(f); return u.s;
}
__device__ __forceinline__ float bf2f_s(short h) {
  union { short s; __hip_bfloat16 b; } u; u.s = h; return __bfloat162float(u.b);
}

__device__ __forceinline__ void glds16(const short* g, short* l) {
  __builtin_amdgcn_global_load_lds((const __attribute__((address_space(1))) void*)g,
                                   (__attribute__((address_space(3))) void*)l, 16, 0, 0);
}

// LDS byte offset of a __shared__-derived pointer (addrspace(3) is 32-bit).
__device__ __forceinline__ unsigned lds_addr(const short* p) {
  return (unsigned)(unsigned long long)(const __attribute__((address_space(3))) short*)p;
}

// Inline-asm ds_read_b128: keeps the counted WAITV authoritative. MUST be
// followed by lgkmcnt(0)+SCHEDB before any consumer (rule 18).
__device__ __forceinline__ s8v dsr128(unsigned a) {
  s8v r;
  asm volatile("ds_read_b128 %0, %1" : "=&v"(r) : "v"(a));
  return r;
}

// ---------------------------------------------------------------------------
// Core NT GEMM, 128x128 tile at (m0,n0), BK=64, LDS double buffer (64 KB).
// Per iter: stage i+1 -> counted WAITV(8) (tile i landed, i+1 in flight) ->
// SBAR -> 2 phases {asm ds_read, lgkmcnt(0), setprio(1), 16 MFMA} -> SBAR.
template <int EPI>
__device__ __forceinline__ void gemm_core(
    const short* __restrict__ A, const short* __restrict__ B,
    short* __restrict__ C, const float* __restrict__ bias,
    short* SMEM, int N, int K, size_t sCz, int m0, int n0, int bz,
    float* __restrict__ Z)
{
  const int tid  = threadIdx.x;
  const int w    = tid >> 6;
  const int lane = tid & 63;
  const int quad = lane >> 4;
  const int l16  = lane & 15;
  const int wm   = (w >> 1) * 64;
  const int wn   = (w & 1) * 64;

  const int strow = tid >> 3;                         // 0..31
  const int gl = ((tid & 7) ^ (strow & 7)) * 8;       // XOR column-octet swizzle

  f4v acc[4][4];
#pragma unroll
  for (int i = 0; i < 4; ++i)
#pragma unroll
    for (int j = 0; j < 4; ++j)
#pragma unroll
      for (int r = 0; r < 4; ++r) acc[i][j][r] = 0.0f;

  const short* Ag = A + (size_t)(m0 + strow) * K + gl;
  const short* Bg = B + (size_t)(n0 + strow) * K + gl;
  const size_t pstr = (size_t)32 * K;
  const int t8 = tid * 8;
  const int swq = l16 & 7;

  const unsigned base = lds_addr(SMEM);
  unsigned aoff[4], boff[4];
#pragma unroll
  for (int ii = 0; ii < 4; ++ii)
    aoff[ii] = base + (unsigned)((wm + ii * 16 + l16) * 128 + ((quad ^ swq) * 16));
#pragma unroll
  for (int j = 0; j < 4; ++j)
    boff[j] = base + 16384u + (unsigned)((wn + j * 16 + l16) * 128 + ((quad ^ swq) * 16));

  const int niter = K >> 6;

#pragma unroll
  for (int p = 0; p < 4; ++p) glds16(Ag + p * pstr, SMEM + t8 + p * 2048);
#pragma unroll
  for (int p = 0; p < 4; ++p) glds16(Bg + p * pstr, SMEM + 8192 + t8 + p * 2048);

  for (int i = 0; i < niter; ++i) {
    const int c = i & 1;
    if (i + 1 < niter) {
      const int k1 = (i + 1) << 6;
      short* dA = SMEM + (1 - c) * 16384 + t8;
#pragma unroll
      for (int p = 0; p < 4; ++p) glds16(Ag + k1 + p * pstr, dA + p * 2048);
#pragma unroll
      for (int p = 0; p < 4; ++p) glds16(Bg + k1 + p * pstr, dA + 8192 + p * 2048);
      SCHEDB();
      WAITV(8);          // tile i landed; tile i+1's 8 stay in flight
    } else {
      WAITV(0);
    }
    SBAR();
    SCHEDB();

    const unsigned cofs = (unsigned)(c << 15);
#pragma unroll
    for (int kk = 0; kk < 2; ++kk) {
      const unsigned kx = (unsigned)(kk << 6);
      s8v af[4], bf[4];
#pragma unroll
      for (int ii = 0; ii < 4; ++ii) af[ii] = dsr128((aoff[ii] ^ kx) + cofs);
#pragma unroll
      for (int j = 0; j < 4; ++j)   bf[j]  = dsr128((boff[j] ^ kx) + cofs);
      WAITL0();
      SCHEDB();
      __builtin_amdgcn_s_setprio(1);
#pragma unroll
      for (int ii = 0; ii < 4; ++ii)
#pragma unroll
        for (int j = 0; j < 4; ++j)
          acc[ii][j] = __builtin_amdgcn_mfma_f32_16x16x32_bf16(af[ii], bf[j], acc[ii][j], 0, 0, 0);
      __builtin_amdgcn_s_setprio(0);
    }
    SBAR();              // buf c free for next iter's prefetch
  }

  // ---- epilogue ----
  float bv[4];
  if (EPI == EPI_BIAS || EPI == EPI_BIAS_T) {
#pragma unroll
    for (int j = 0; j < 4; ++j) bv[j] = bias[n0 + wn + j * 16 + l16];
  }

  if (EPI == EPI_BIAS_T) {
#pragma unroll
    for (int i = 0; i < 4; ++i) {
#pragma unroll
      for (int j = 0; j < 4; ++j) {
        const int gn  = n0 + wn + j * 16 + l16;
        const int gmb = m0 + wm + i * 16 + quad * 4;
        const int bb = gmb >> 11, ssb = gmb & (S_LEN - 1);
        s4v o;
#pragma unroll
        for (int r = 0; r < 4; ++r) o[r] = f2bf_s(acc[i][j][r] + bv[j]);
        *(s4v*)&C[((size_t)bb * D_DIM + gn) * S_LEN + ssb] = o;
      }
    }
    return;
  }

  // EPI_BIAS / EPI_SCORES: LDS transpose -> coalesced 16B row stores.
  short* TB = SMEM;                 // 4 waves x 2176 shorts (32 rows x stride 68)
  const int wbase = w * 2176;
  float csum[4] = {0.f, 0.f, 0.f, 0.f};

#pragma unroll
  for (int ph = 0; ph < 2; ++ph) {
    __syncthreads();
#pragma unroll
    for (int ii = 0; ii < 2; ++ii) {
      const int i = ph * 2 + ii;
#pragma unroll
      for (int j = 0; j < 4; ++j) {
        const int gn = n0 + wn + j * 16 + l16;
#pragma unroll
        for (int r = 0; r < 4; ++r) {
          short o;
          if (EPI == EPI_SCORES) {
            const int gm = m0 + wm + i * 16 + quad * 4 + r;
            const float f = (gm >= gn) ? (__expf(acc[i][j][r] * SCALE_F) - 1.0f) : 0.0f;
            csum[j] += f;
            o = f2bf_s(f);
          } else {
            o = f2bf_s(acc[i][j][r] + bv[j]);
          }
          TB[wbase + (ii * 16 + quad * 4 + r) * 68 + j * 16 + l16] = o;
        }
      }
    }
    __syncthreads();
#pragma unroll
    for (int p = 0; p < 4; ++p) {
      const int row = p * 8 + (lane >> 3);   // 0..31
      const int cg  = lane & 7;
      const s8v vv = *(const s8v*)&TB[wbase + row * 68 + cg * 8];
      const int gm = m0 + wm + ph * 32 + row;
      const int gn = n0 + wn + cg * 8;
      *(s8v*)&C[sCz + (size_t)gm * N + gn] = vv;
    }
  }

  if (EPI == EPI_SCORES) {
#pragma unroll
    for (int j = 0; j < 4; ++j) {
      float cs = csum[j];
      cs += __shfl_xor(cs, 16, 64);
      cs += __shfl_xor(cs, 32, 64);
      if (quad == 0) atomicAdd(&Z[(bz << 11) + n0 + wn + j * 16 + l16], cs);
    }
  }
}

// projections q,k only: 512 full tiles = exactly one dispatch round @2/CU.
__global__ __launch_bounds__(256, 2) void proj_qk(
    const short* __restrict__ a0, const short* __restrict__ a1,
    const short* __restrict__ b0, const short* __restrict__ b1,
    short* __restrict__ c0, short* __restrict__ c1,
    const float* __restrict__ x0, const float* __restrict__ x1)
{
  __shared__ __align__(16) short SMEM[32768];   // 64 KB
  const int bid = blockIdx.x;
  const int bsw = (bid & 7) * 64 + (bid >> 3);  // XCD-bijective (512 = 8x64)
  const int z   = bsw >> 8;                     // 0 or 1
  const int rem = bsw & 255;
  const int m0  = (rem >> 2) * 128;
  const int n0  = (rem & 3) * 128;
  const short* A = z ? a1 : a0;
  const short* B = z ? b1 : b0;
  short*       C = z ? c1 : c0;
  const float* bias = z ? x1 : x0;
  gemm_core<EPI_BIAS>(A, B, C, bias, SMEM, D_DIM, D_DIM, 0, m0, n0, 0, nullptr);
}

// Fused: 544 scores tiles (compact lower-tri, need qp/kp) + 256 vpT
// projection tiles (need only vb/Wvb, which live in d_out scratch — OUTSIDE
// F's region, so the concurrent F writes cannot clobber them). 800 blocks =
// 2 rounds; the vpT tiles fill scores' otherwise near-empty tail round.
__global__ __launch_bounds__(256, 2) void scores_projv(
    const short* __restrict__ qp, const short* __restrict__ kp, short* __restrict__ F,
    float* __restrict__ Z,
    const short* __restrict__ vb, const short* __restrict__ Wvb,
    short* __restrict__ vpT, const float* __restrict__ xv)
{
  __shared__ __align__(16) short SMEM[32768];   // 64 KB
  const int bid = blockIdx.x;
  if (bid < 544) {
    const int bsw = (bid & 7) * 68 + (bid >> 3);  // XCD-bijective (544 = 8x68)
    const int bz  = bsw / 136;
    const int t   = bsw - bz * 136;
    int ti = (int)((sqrtf(8.0f * t + 1.0f) - 1.0f) * 0.5f);
    while ((ti + 1) * (ti + 2) / 2 <= t) ++ti;
    while (ti * (ti + 1) / 2 > t) --ti;
    const int tj = t - ti * (ti + 1) / 2;         // tj <= ti
    gemm_core<EPI_SCORES>(qp + (size_t)bz * S_LEN * D_DIM, kp + (size_t)bz * S_LEN * D_DIM,
                          F, nullptr, SMEM, S_LEN, D_DIM,
                          (size_t)bz * S_LEN * S_LEN, ti * 128, tj * 128, bz, Z);
  } else {
    const int h   = bid - 544;                    // 0..255
    const int hsw = (h & 7) * 32 + (h >> 3);      // XCD-bijective (256 = 8x32)
    const int m0  = (hsw >> 2) * 128;             // 64 row-tiles of [8192]
    const int n0  = (hsw & 3) * 128;
    gemm_core<EPI_BIAS_T>(vb, Wvb, vpT, xv, SMEM, D_DIM, D_DIM, 0, m0, n0, 0, nullptr);
  }
}

// out = F @ vpT'^T + T, 64x128 tiles, BK=64, K truncated at m0+64,
// triple-buffered (72 KB), prefetch distance 2 issued AFTER the barrier.
// Grid 512 1-D: h -> n0=(h&3)*128, bz=(h>>2)&3, zs=h>>4; co-resident pairs
// (h, h+256) get complementary niter (sum 33); long blocks dispatch first.
__global__ __launch_bounds__(256, 2) void gemm_outF(
    const short* __restrict__ F, const short* __restrict__ vpT,
    const float* __restrict__ Tv, float* __restrict__ out)
{
  __shared__ __align__(16) short SMEM[36864];   // 72 KB

  const int tid  = threadIdx.x;
  const int h    = blockIdx.x;
  const int n0   = (h & 3) * 128;
  const int bz   = (h >> 2) & 3;
  const int zs   = h >> 4;                      // 0..31
  const int mi   = (zs < 16) ? (31 - zs) : (zs - 16);
  const int m0   = mi * 64;

  const short* A = F   + (size_t)bz * S_LEN * S_LEN;
  const short* B = vpT + (size_t)bz * D_DIM * S_LEN;

  const int w    = tid >> 6;
  const int lane = tid & 63;
  const int quad = lane >> 4;
  const int l16  = lane & 15;
  const int wm   = (w >> 1) * 32;
  const int wn   = (w & 1) * 64;

  const int strow = tid >> 3;
  const int gl = ((tid & 7) ^ (strow & 7)) * 8;

  f4v acc[2][4];
#pragma unroll
  for (int i = 0; i < 2; ++i)
#pragma unroll
    for (int j = 0; j < 4; ++j)
#pragma unroll
      for (int r = 0; r < 4; ++r) acc[i][j][r] = 0.0f;

  const short* Ag = A + (size_t)(m0 + strow) * S_LEN + gl;
  const short* Bg = B + (size_t)(n0 + strow) * S_LEN + gl;
  const size_t pstr = (size_t)32 * S_LEN;
  const int t8 = tid * 8;
  const int swq = l16 & 7;

  const unsigned base = lds_addr(SMEM);
  unsigned aoff[2], boff[4];
#pragma unroll
  for (int ii = 0; ii < 2; ++ii)
    aoff[ii] = base + (unsigned)((wm + ii * 16 + l16) * 128 + ((quad ^ swq) * 16));
#pragma unroll
  for (int j = 0; j < 4; ++j)
    boff[j] = base + 8192u + (unsigned)((wn + j * 16 + l16) * 128 + ((quad ^ swq) * 16));

  const int niter = mi + 1;   // K runs 0 .. m0+64

  // preload tiles 0,1 into bufs 0,1 (6 loads each: A x2, B x4)
#pragma unroll
  for (int pre = 0; pre < 2; ++pre) {
    short* dst = SMEM + pre * 12288 + t8;
    const int k0 = pre << 6;
#pragma unroll
    for (int p = 0; p < 2; ++p) glds16(Ag + k0 + p * pstr, dst + p * 2048);
#pragma unroll
    for (int p = 0; p < 4; ++p) glds16(Bg + k0 + p * pstr, dst + 4096 + p * 2048);
  }

  int cbuf = 0;
  for (int i = 0; i < niter; ++i) {
    if (i + 1 < niter) { WAITV(6); } else { WAITV(0); }   // tile i landed
    SBAR();
    SCHEDB();

    if (i + 2 < niter) {          // issue i+2 into the buffer read at i-1
      int nb = cbuf + 2; if (nb >= 3) nb -= 3;
      const int k2 = (i + 2) << 6;
      short* dst = SMEM + nb * 12288 + t8;
#pragma unroll
      for (int p = 0; p < 2; ++p) glds16(Ag + k2 + p * pstr, dst + p * 2048);
#pragma unroll
      for (int p = 0; p < 4; ++p) glds16(Bg + k2 + p * pstr, dst + 4096 + p * 2048);
      SCHEDB();
    }

    const unsigned cofs = (unsigned)(cbuf * 24576);
    cbuf = (cbuf == 2) ? 0 : cbuf + 1;
#pragma unroll
    for (int kk = 0; kk < 2; ++kk) {
      const unsigned kx = (unsigned)(kk << 6);
      s8v af[2], bf[4];
#pragma unroll
      for (int ii = 0; ii < 2; ++ii) af[ii] = dsr128((aoff[ii] ^ kx) + cofs);
#pragma unroll
      for (int j = 0; j < 4; ++j)   bf[j]  = dsr128((boff[j] ^ kx) + cofs);
      WAITL0();
      SCHEDB();
      __builtin_amdgcn_s_setprio(1);
#pragma unroll
      for (int ii = 0; ii < 2; ++ii)
#pragma unroll
        for (int j = 0; j < 4; ++j)
          acc[ii][j] = __builtin_amdgcn_mfma_f32_16x16x32_bf16(af[ii], bf[j], acc[ii][j], 0, 0, 0);
      __builtin_amdgcn_s_setprio(0);
    }
  }

  float* Cf = out + (size_t)bz * S_LEN * D_DIM;
#pragma unroll
  for (int i = 0; i < 2; ++i) {
#pragma unroll
    for (int j = 0; j < 4; ++j) {
      const int gn = n0 + wn + j * 16 + l16;
      const float tvn = Tv[(bz << 9) + gn];
#pragma unroll
      for (int r = 0; r < 4; ++r) {
        const int gm = m0 + wm + i * 16 + quad * 4 + r;
        Cf[(size_t)gm * D_DIM + gn] = acc[i][j][r] + tvn;
      }
    }
  }
}

// fp32 -> bf16, one launch for data (x<2048) and weights (x>=2048); zeroes ZF.
__global__ __launch_bounds__(256) void cvt_all(
    const float* __restrict__ q, const float* __restrict__ k, const float* __restrict__ v,
    const float* __restrict__ wq, const float* __restrict__ wk, const float* __restrict__ wv,
    short* __restrict__ qb, short* __restrict__ kb, short* __restrict__ vb,
    short* __restrict__ Wqb, short* __restrict__ Wkb, short* __restrict__ Wvb,
    float* __restrict__ ZF)
{
  const int y = blockIdx.y;
  const float* s; short* d; int i;
  if (blockIdx.x < 2048) {
    s = (y == 0) ? q : (y == 1) ? k : v;
    d = (y == 0) ? qb : (y == 1) ? kb : vb;
    i = (blockIdx.x * 256 + threadIdx.x) * 8;
    if (y == 0) {
      const int gid = blockIdx.x * 256 + threadIdx.x;
      if (gid < 8192) ZF[gid] = 0.0f;
    }
  } else {
    s = (y == 0) ? wq : (y == 1) ? wk : wv;
    d = (y == 0) ? Wqb : (y == 1) ? Wkb : Wvb;
    i = ((int)(blockIdx.x - 2048) * 256 + threadIdx.x) * 8;
  }
  const float4 f0 = *(const float4*)(s + i);
  const float4 f1 = *(const float4*)(s + i + 4);
  s8v o;
  o[0] = f2bf_s(f0.x); o[1] = f2bf_s(f0.y); o[2] = f2bf_s(f0.z); o[3] = f2bf_s(f0.w);
  o[4] = f2bf_s(f1.x); o[5] = f2bf_s(f1.y); o[6] = f2bf_s(f1.z); o[7] = f2bf_s(f1.w);
  *(s8v*)(d + i) = o;
}

// block per (b,d): vpT[b][d][k] /= (2048+ZF[b][k]); Tv[b,d] = sum_k (fp32)
__global__ __launch_bounds__(256) void scale_vpt_T(
    short* __restrict__ vpT, const float* __restrict__ ZF, float* __restrict__ Tv)
{
  __shared__ float red[4];
  const int b = blockIdx.y, d = blockIdx.x, tid = threadIdx.x;
  const size_t rowbase = ((size_t)(b * D_DIM + d)) * S_LEN;
  const float* zf = ZF + (b << 11);
  const int k0 = tid * 8;

  s8v v = *(s8v*)&vpT[rowbase + k0];
  float s = 0.0f;
#pragma unroll
  for (int i = 0; i < 8; ++i) {
    const float w = bf2f_s(v[i]) / (2048.0f + zf[k0 + i]);
    s += w;
    v[i] = f2bf_s(w);
  }
  *(s8v*)&vpT[rowbase + k0] = v;

#pragma unroll
  for (int off = 32; off >= 1; off >>= 1) s += __shfl_xor(s, off, 64);
  if ((tid & 63) == 0) red[tid >> 6] = s;
  __syncthreads();
  if (tid == 0) Tv[(b << 9) + d] = red[0] + red[1] + red[2] + red[3];
}

extern "C" void kernel_launch(void* const* d_in, const int* in_sizes, int n_in,
                              void* d_out, int out_size, void* d_ws, size_t ws_size,
                              hipStream_t stream) {
  const float* q   = (const float*)d_in[0];
  const float* k   = (const float*)d_in[1];
  const float* v   = (const float*)d_in[2];
  const float* WQw = (const float*)d_in[3];
  const float* WQb = (const float*)d_in[4];
  const float* WKw = (const float*)d_in[5];
  const float* WKb = (const float*)d_in[6];
  const float* WVw = (const float*)d_in[7];
  const float* WVb = (const float*)d_in[8];

  char* ws = (char*)d_ws;
  // F occupies ws[0,32M). qb/kb/Wqb/Wkb alias F (dead before any F write).
  // vb and Wvb must SURVIVE into scores_projv (concurrent with F writes), so
  // they live in d_out scratch: out is 16MB and only written by the final
  // outF phase, which fully overwrites it.
  short* F   = (short*)(ws);                 // 32 MB  [4][2048][2048] (lower tiles only)
  short* qb  = (short*)(ws);                 //  8 MB  (alias F, dead after proj_qk)
  short* kb  = qb + 4194304;                 //  8 MB  (alias F)
  short* Wqb = (short*)(ws + 25165824);      //  512 KB (alias F, dead after proj_qk)
  short* Wkb = Wqb + 262144;                 //  512 KB (alias F)
  short* qp  = (short*)(ws + 33554432);      //  8 MB  [4][2048][512]
  short* kp  = (short*)(ws + 41943040);      //  8 MB
  short* vpT = (short*)(ws + 50331648);      //  8 MB  [4][512][2048]
  float* ZF  = (float*)(ws + 58720256);      // 32 KB  [4][2048]
  float* Tv  = (float*)(ws + 58753024);      //  8 KB  [4][512]
  short* vb  = (short*)d_out;                //  8 MB  (out scratch [0,8M))
  short* Wvb = (short*)d_out + 4194304;      //  512 KB (out scratch [8M,8.5M))

  const dim3 blk(256);

  cvt_all<<<dim3(2176, 3), blk, 0, stream>>>(
      q, k, v, WQw, WKw, WVw, qb, kb, vb, Wqb, Wkb, Wvb, ZF);

  // q,k projections: 512 full tiles = exactly one round @2/CU
  proj_qk<<<dim3(512), blk, 0, stream>>>(qb, kb, Wqb, Wkb, qp, kp, WQb, WKb);

  // scores (544) + independent vpT projection (256) fused: 2 rounds
  scores_projv<<<dim3(800), blk, 0, stream>>>(qp, kp, F, ZF, vb, Wvb, vpT, WVb);

  // vpT' = vpT/(2048+ZF); Tv = rowsum(vpT')
  scale_vpt_T<<<dim3(512, 4), blk, 0, stream>>>(vpT, ZF, Tv);

  // out = F @ vpT'^T + Tv: 64x128 tiles, K truncated at m0+64, balanced pairs
  gemm_outF<<<dim3(512), blk, 0, stream>>>(F, vpT, Tv, (float*)d_out);
}